// Round 4
// baseline (2785.292 us; speedup 1.0000x reference)
//
#include <hip/hip_runtime.h>
#include <cstdint>
#include <cstddef>

// ---------------- problem constants (fixed by setup_inputs) ----------------
static constexpr int V3   = 100000;
static constexpr int VM   = 25000;
static constexpr int KE   = 128;
static constexpr int E3   = 800000;
static constexpr int EM   = 200000;
static constexpr int C3   = 128;
static constexpr int CMID = 256;

typedef unsigned short u16;
typedef unsigned int   u32;
using short8v = __attribute__((ext_vector_type(8))) short;
using f32x4   = __attribute__((ext_vector_type(4))) float;

#define DEVI __device__ __forceinline__
DEVI float4 ld4(const float* p){ return *(const float4*)p; }
DEVI void   st4(float* p, float4 v){ *(float4*)p = v; }
DEVI float  bf2f(u16 u){ return __uint_as_float(((u32)u) << 16); }
DEVI u16    f2bf(float f){
  u32 u = __float_as_uint(f);
  u += 0x7FFFu + ((u >> 16) & 1u);   // RNE
  return (u16)(u >> 16);
}
DEVI u32 pk2(float a, float b){ return (u32)f2bf(a) | ((u32)f2bf(b) << 16); }
// LDS tile addressing: rows of 32 u16 (4 octets of 8), stride 40 u16,
// octet XOR-swizzled by row to kill 8-way staging-write bank conflicts.
DEVI int lofs(int row, int oct){ return row * 40 + ((oct ^ ((row >> 3) & 3)) << 3); }

static inline int cdiv(int a, int b){ return (a + b - 1) / b; }

// =====================================================================
// MFMA GEMM: OUT[v][:] = act( concat(A0,A1,A2)[v,:] @ W + bias (+res) )
// BM=128 rows/block, BN=128 col window (blockIdx.y), 4 waves, register
// prefetch double-buffer. A sources f32 (aty=0) or bf16 (aty=1); W is
// pre-transposed bf16 Wt[n][k]. In-place over a row-aligned A source is
// safe ONLY when gridDim.y==1 (block reads/writes its own 128-row stripe).
// =====================================================================
template<bool RELU, bool RES, bool GATHER, bool OBF16>
__global__ __launch_bounds__(256)
void k_mgemm(const void* __restrict__ A0, int aty0, int K0,
             const u16* __restrict__ wt0, int wl0, int wo0,
             const void* __restrict__ A1, int aty1, int K1,
             const u16* __restrict__ wt1, int wl1, int wo1,
             const void* __restrict__ A2, int aty2, int K2,
             const u16* __restrict__ wt2, int wl2, int wo2,
             const int* __restrict__ gidx,
             const float* __restrict__ bias, const float* __restrict__ res,
             void* __restrict__ OUT, int CO, int V)
{
  __shared__ __align__(16) u16 As[128 * 40];
  __shared__ __align__(16) u16 Ws[128 * 40];

  const int tid  = threadIdx.x;
  const int wave = tid >> 6, lane = tid & 63;
  const int vbase = blockIdx.x * 128;
  const int ncol0 = blockIdx.y * 128;
  const int KT = K0 + K1 + K2;

  f32x4 acc[2][8];
  #pragma unroll
  for (int r = 0; r < 2; r++)
    #pragma unroll
    for (int n = 0; n < 8; n++) { acc[r][n][0]=0.f; acc[r][n][1]=0.f; acc[r][n][2]=0.f; acc[r][n][3]=0.f; }

  const int ar = tid >> 1, aoct0 = (tid & 1) * 2;
  const int arow = vbase + ar;
  int grow0 = arow;
  if (GATHER && arow < V) grow0 = gidx[arow];
  const int wcol = tid & 127, woct0 = (tid >> 7) * 2;

  auto fetchA = [&](int kg) -> uint4 {
    if (arow >= V || kg >= KT) return make_uint4(0,0,0,0);
    const void* src; int aty, koff, sK;
    if (kg < K0)           { src=A0; aty=aty0; koff=0;     sK=K0; }
    else if (kg < K0 + K1) { src=A1; aty=aty1; koff=K0;    sK=K1; }
    else                   { src=A2; aty=aty2; koff=K0+K1; sK=K2; }
    int row = (GATHER && kg < K0) ? grow0 : arow;
    int kl = kg - koff;
    if (aty) return *(const uint4*)((const u16*)src + (size_t)row * sK + kl);
    const float* fp = (const float*)src + (size_t)row * sK + kl;
    float4 x = ld4(fp), y = ld4(fp + 4);
    return make_uint4(pk2(x.x,x.y), pk2(x.z,x.w), pk2(y.x,y.y), pk2(y.z,y.w));
  };
  auto fetchW = [&](int kg) -> uint4 {
    if (kg >= KT) return make_uint4(0,0,0,0);
    const u16* wt; int koff, wl, wo;
    if (kg < K0)           { wt=wt0; koff=0;     wl=wl0; wo=wo0; }
    else if (kg < K0 + K1) { wt=wt1; koff=K0;    wl=wl1; wo=wo1; }
    else                   { wt=wt2; koff=K0+K1; wl=wl2; wo=wo2; }
    return *(const uint4*)(wt + (size_t)(ncol0 + wcol) * wl + wo + (kg - koff));
  };

  uint4 pa0 = fetchA(aoct0 * 8), pa1 = fetchA(aoct0 * 8 + 8);
  uint4 pw0 = fetchW(woct0 * 8), pw1 = fetchW(woct0 * 8 + 8);

  for (int kt = 0; kt < KT; kt += 32) {
    __syncthreads();   // previous tile's MFMA reads done
    *(uint4*)&As[lofs(ar, aoct0)]     = pa0;
    *(uint4*)&As[lofs(ar, aoct0 + 1)] = pa1;
    *(uint4*)&Ws[lofs(wcol, woct0)]     = pw0;
    *(uint4*)&Ws[lofs(wcol, woct0 + 1)] = pw1;
    __syncthreads();   // tile ready
    int kn = kt + 32;
    if (kn < KT) {     // prefetch next tile; completes under MFMA below
      pa0 = fetchA(kn + aoct0 * 8); pa1 = fetchA(kn + aoct0 * 8 + 8);
      pw0 = fetchW(kn + woct0 * 8); pw1 = fetchW(kn + woct0 * 8 + 8);
    }
    const int kc = lane >> 4, ml = lane & 15;
    #pragma unroll
    for (int r = 0; r < 2; r++) {
      int mrow = wave * 32 + r * 16 + ml;
      short8v a = *(const short8v*)(const void*)&As[lofs(mrow, kc)];
      #pragma unroll
      for (int n = 0; n < 8; n++) {
        short8v b = *(const short8v*)(const void*)&Ws[lofs(n * 16 + ml, kc)];
        acc[r][n] = __builtin_amdgcn_mfma_f32_16x16x32_bf16(a, b, acc[r][n], 0, 0, 0);
      }
    }
  }

  const int q4 = (lane >> 4) * 4, colb = lane & 15;
  #pragma unroll
  for (int r = 0; r < 2; r++)
  #pragma unroll
  for (int n = 0; n < 8; n++) {
    int gcol = ncol0 + n * 16 + colb;
    float bv = bias ? bias[gcol] : 0.f;
    #pragma unroll
    for (int q = 0; q < 4; q++) {
      int grow = vbase + wave * 32 + r * 16 + q4 + q;
      if (grow >= V) continue;
      float o = acc[r][n][q] + bv;
      if (RES) o += res[(size_t)grow * CO + gcol];
      if (RELU) o = fmaxf(o, 0.f);
      if (OBF16) ((u16*)OUT)[(size_t)grow * CO + gcol] = f2bf(o);
      else       ((float*)OUT)[(size_t)grow * CO + gcol] = o;
    }
  }
}

// =====================================================================
// MFMA megagate: BM=64 rows, BN=128 cols (blockIdx.y windows for CO=256),
// register prefetch. gx=GEX@S gy=GEY@S br=GEX@Tr-GEY@Ti bi=GEX@Ti+GEY@Tr
// GF = tanh(gx*br+gy*bi) -> bf16.
// =====================================================================
__global__ __launch_bounds__(256)
void k_mgate(const u16* __restrict__ GEX, const u16* __restrict__ GEY,
             const u16* __restrict__ St, const u16* __restrict__ Trt,
             const u16* __restrict__ Tit,
             u16* __restrict__ GF, int CO, int V)
{
  __shared__ __align__(16) u16 Ax[64*40], Ay[64*40], An[64*40];
  __shared__ __align__(16) u16 Bs[128*40], Br_[128*40], Bi_[128*40];

  const int tid = threadIdx.x;
  const int wave = tid >> 6, lane = tid & 63;
  const int vbase = blockIdx.x * 64;
  const int ncol0 = blockIdx.y * 128;

  f32x4 gx[8], gy[8], br[8], bi[8];
  #pragma unroll
  for (int n = 0; n < 8; n++)
    #pragma unroll
    for (int q = 0; q < 4; q++) { gx[n][q]=0.f; gy[n][q]=0.f; br[n][q]=0.f; bi[n][q]=0.f; }

  const int ar = tid >> 2, aoct = tid & 3;
  const int arow = vbase + ar;
  const int wcol = tid & 127, woct0 = (tid >> 7) * 2;

  uint4 zx = make_uint4(0,0,0,0), zy = make_uint4(0,0,0,0);
  if (arow < V) {
    zx = *(const uint4*)(GEX + (size_t)arow * KE + aoct * 8);
    zy = *(const uint4*)(GEY + (size_t)arow * KE + aoct * 8);
  }
  size_t wb = (size_t)(ncol0 + wcol) * KE + woct0 * 8;
  uint4 ps0 = *(const uint4*)(St + wb),  ps1 = *(const uint4*)(St + wb + 8);
  uint4 pr0 = *(const uint4*)(Trt + wb), pr1 = *(const uint4*)(Trt + wb + 8);
  uint4 pi0 = *(const uint4*)(Tit + wb), pi1 = *(const uint4*)(Tit + wb + 8);

  for (int kt = 0; kt < KE; kt += 32) {
    __syncthreads();
    uint4 zn = make_uint4(zy.x ^ 0x80008000u, zy.y ^ 0x80008000u,
                          zy.z ^ 0x80008000u, zy.w ^ 0x80008000u);
    *(uint4*)&Ax[lofs(ar, aoct)] = zx;
    *(uint4*)&Ay[lofs(ar, aoct)] = zy;
    *(uint4*)&An[lofs(ar, aoct)] = zn;
    *(uint4*)&Bs[lofs(wcol, woct0)]      = ps0;
    *(uint4*)&Bs[lofs(wcol, woct0 + 1)]  = ps1;
    *(uint4*)&Br_[lofs(wcol, woct0)]     = pr0;
    *(uint4*)&Br_[lofs(wcol, woct0 + 1)] = pr1;
    *(uint4*)&Bi_[lofs(wcol, woct0)]     = pi0;
    *(uint4*)&Bi_[lofs(wcol, woct0 + 1)] = pi1;
    __syncthreads();
    int kn = kt + 32;
    if (kn < KE) {
      if (arow < V) {
        zx = *(const uint4*)(GEX + (size_t)arow * KE + kn + aoct * 8);
        zy = *(const uint4*)(GEY + (size_t)arow * KE + kn + aoct * 8);
      }
      size_t w2 = (size_t)(ncol0 + wcol) * KE + kn + woct0 * 8;
      ps0 = *(const uint4*)(St + w2);  ps1 = *(const uint4*)(St + w2 + 8);
      pr0 = *(const uint4*)(Trt + w2); pr1 = *(const uint4*)(Trt + w2 + 8);
      pi0 = *(const uint4*)(Tit + w2); pi1 = *(const uint4*)(Tit + w2 + 8);
    }
    const int kc = lane >> 4, ml = lane & 15;
    int mrow = wave * 16 + ml;
    short8v ax = *(const short8v*)(const void*)&Ax[lofs(mrow, kc)];
    short8v ay = *(const short8v*)(const void*)&Ay[lofs(mrow, kc)];
    short8v an = *(const short8v*)(const void*)&An[lofs(mrow, kc)];
    #pragma unroll
    for (int n = 0; n < 8; n++) {
      int bofs = lofs(n * 16 + ml, kc);
      short8v bs  = *(const short8v*)(const void*)&Bs[bofs];
      short8v brv = *(const short8v*)(const void*)&Br_[bofs];
      short8v biv = *(const short8v*)(const void*)&Bi_[bofs];
      gx[n] = __builtin_amdgcn_mfma_f32_16x16x32_bf16(ax, bs,  gx[n], 0,0,0);
      gy[n] = __builtin_amdgcn_mfma_f32_16x16x32_bf16(ay, bs,  gy[n], 0,0,0);
      br[n] = __builtin_amdgcn_mfma_f32_16x16x32_bf16(ax, brv, br[n], 0,0,0);
      br[n] = __builtin_amdgcn_mfma_f32_16x16x32_bf16(an, biv, br[n], 0,0,0);
      bi[n] = __builtin_amdgcn_mfma_f32_16x16x32_bf16(ax, biv, bi[n], 0,0,0);
      bi[n] = __builtin_amdgcn_mfma_f32_16x16x32_bf16(ay, brv, bi[n], 0,0,0);
    }
  }

  const int q4 = (lane >> 4) * 4, colb = lane & 15;
  #pragma unroll
  for (int n = 0; n < 8; n++) {
    int gcol = ncol0 + n * 16 + colb;
    #pragma unroll
    for (int q = 0; q < 4; q++) {
      int grow = vbase + wave * 16 + q4 + q;
      if (grow >= V) continue;
      float o = tanhf(gx[n][q] * br[n][q] + gy[n][q] * bi[n][q]);
      GF[(size_t)grow * CO + gcol] = f2bf(o);
    }
  }
}

// =====================================================================
// MFMA spectral down-projection: SPEC[ke][c] += sum_v E[v][ke]*X[v][c]*m[v]
// Split-K + f32 atomics; register prefetch. grid: x=K-chunk, y=m-half(64),
// z=col-window(128).
// =====================================================================
__global__ __launch_bounds__(256)
void k_specmm(const float* __restrict__ E, const float* __restrict__ X,
              const float* __restrict__ mass, float* __restrict__ SPEC,
              int C, int V, int CH)
{
  __shared__ __align__(16) u16 As[64 * 40];
  __shared__ __align__(16) u16 Bs[128 * 40];

  const int tid = threadIdx.x;
  const int wave = tid >> 6, lane = tid & 63;
  const int m0 = blockIdx.y * 64;
  const int n0 = blockIdx.z * 128;
  const int vs = blockIdx.x * CH;
  const int ve = min(V, vs + CH);

  f32x4 acc[8];
  #pragma unroll
  for (int n = 0; n < 8; n++) { acc[n][0]=0.f; acc[n][1]=0.f; acc[n][2]=0.f; acc[n][3]=0.f; }

  const int am = tid & 63, ac = tid >> 6;        // A: col m0+am, v-octet ac
  const int bcol = tid & 127, bc0 = (tid >> 7) * 2; // B: col n0+bcol, octets bc0,bc0+1

  float fa[8], fb0[8], fb1[8], fm0[8], fm1[8];
  auto loadA = [&](int kt) {
    #pragma unroll
    for (int j = 0; j < 8; j++) {
      int v = kt + ac * 8 + j;
      fa[j] = (v < ve) ? E[(size_t)v * KE + m0 + am] : 0.f;
    }
  };
  auto loadB = [&](int kt) {
    #pragma unroll
    for (int j = 0; j < 8; j++) {
      int v0 = kt + bc0 * 8 + j, v1 = v0 + 8;
      fb0[j] = (v0 < ve) ? X[(size_t)v0 * C + n0 + bcol] : 0.f;
      fm0[j] = (v0 < ve) ? mass[v0] : 0.f;
      fb1[j] = (v1 < ve) ? X[(size_t)v1 * C + n0 + bcol] : 0.f;
      fm1[j] = (v1 < ve) ? mass[v1] : 0.f;
    }
  };
  loadA(vs); loadB(vs);

  for (int kt = vs; kt < ve; kt += 32) {
    __syncthreads();
    *(uint4*)&As[lofs(am, ac)] = make_uint4(
        pk2(fa[0],fa[1]), pk2(fa[2],fa[3]), pk2(fa[4],fa[5]), pk2(fa[6],fa[7]));
    float t0[8], t1[8];
    #pragma unroll
    for (int j = 0; j < 8; j++) { t0[j] = fb0[j]*fm0[j]; t1[j] = fb1[j]*fm1[j]; }
    *(uint4*)&Bs[lofs(bcol, bc0)] = make_uint4(
        pk2(t0[0],t0[1]), pk2(t0[2],t0[3]), pk2(t0[4],t0[5]), pk2(t0[6],t0[7]));
    *(uint4*)&Bs[lofs(bcol, bc0 + 1)] = make_uint4(
        pk2(t1[0],t1[1]), pk2(t1[2],t1[3]), pk2(t1[4],t1[5]), pk2(t1[6],t1[7]));
    __syncthreads();
    if (kt + 32 < ve) { loadA(kt + 32); loadB(kt + 32); }
    const int kc = lane >> 4, ml = lane & 15;
    short8v a = *(const short8v*)(const void*)&As[lofs(wave * 16 + ml, kc)];
    #pragma unroll
    for (int n = 0; n < 8; n++) {
      short8v b = *(const short8v*)(const void*)&Bs[lofs(n * 16 + ml, kc)];
      acc[n] = __builtin_amdgcn_mfma_f32_16x16x32_bf16(a, b, acc[n], 0, 0, 0);
    }
  }

  const int q4 = (lane >> 4) * 4, colb = lane & 15;
  #pragma unroll
  for (int n = 0; n < 8; n++) {
    int col = n0 + n * 16 + colb;
    #pragma unroll
    for (int q = 0; q < 4; q++) {
      int row = m0 + wave * 16 + q4 + q;
      unsafeAtomicAdd(&SPEC[(size_t)row * C + col], acc[n][q]);
    }
  }
}

// =====================================================================
// smallprep: S = exp(-evals*max(dt,1e-8))*SPEC; outputs bf16 TRANSPOSED
// St/Trt/Tit [CO][128] (Tr=S@Are, Ti=S@Aim) and SWt = (S@w0b)^T [CO][128]
// =====================================================================
template<int C>
__global__ void k_smallprep(const float* __restrict__ SPEC, const float* __restrict__ evals,
                            const float* __restrict__ dt, const float* __restrict__ Are,
                            const float* __restrict__ Aim, const float* __restrict__ w0,
                            u16* __restrict__ St, u16* __restrict__ Trt,
                            u16* __restrict__ Tit, u16* __restrict__ SWt)
{
  __shared__ float sld[C];
  const int k = blockIdx.x;
  const int c = threadIdx.x;
  const float ev = evals[k];
  float s = expf(-ev * fmaxf(dt[c], 1e-8f)) * SPEC[(size_t)k * C + c];
  sld[c] = s;
  St[(size_t)c * 128 + k] = f2bf(s);
  __syncthreads();
  float tr = 0.f, ti = 0.f, sw = 0.f;
  for (int j = 0; j < C; j++) {
    float sj = sld[j];
    tr = fmaf(sj, Are[(size_t)j * C + c], tr);
    ti = fmaf(sj, Aim[(size_t)j * C + c], ti);
    sw = fmaf(sj, w0[(size_t)(C + j) * C + c], sw);
  }
  Trt[(size_t)c * 128 + k] = f2bf(tr);
  Tit[(size_t)c * 128 + k] = f2bf(ti);
  SWt[(size_t)c * 128 + k] = f2bf(sw);
}

// ===== weight pre-transpose f32[K][N] -> bf16 Wt[N][K] (z batches) =====
__global__ void k_prepw(const float* __restrict__ W, u16* __restrict__ WT, int K, int N) {
  size_t zoff = (size_t)blockIdx.z * K * N;
  int i = blockIdx.x * 256 + threadIdx.x;
  if (i < K * N) {
    int k = i / N, n = i % N;
    WT[zoff + (size_t)n * K + k] = f2bf(W[zoff + i]);
  }
}

// ============================ CSR build ==============================
__global__ void k_hist(const int* __restrict__ idx, int* __restrict__ deg, int E) {
  int e = blockIdx.x * 256 + threadIdx.x;
  if (e < E) atomicAdd(&deg[idx[2 * e]], 1);
}
__global__ void k_scan1(const int* __restrict__ deg, int* __restrict__ excl,
                        int* __restrict__ bsum, int V) {
  __shared__ int sd[256];
  int t = threadIdx.x;
  int i = blockIdx.x * 256 + t;
  int v = (i < V) ? deg[i] : 0;
  sd[t] = v;
  __syncthreads();
  for (int off = 1; off < 256; off <<= 1) {
    int add = (t >= off) ? sd[t - off] : 0;
    __syncthreads();
    sd[t] += add;
    __syncthreads();
  }
  if (i < V) excl[i] = sd[t] - v;
  if (t == 255) bsum[blockIdx.x] = sd[255];
}
__global__ void k_scan2(int* __restrict__ bsum, int nb, int* __restrict__ rowptr, int V) {
  __shared__ int sd[512];
  int t = threadIdx.x;
  int v = (t < nb) ? bsum[t] : 0;
  sd[t] = v;
  __syncthreads();
  for (int off = 1; off < 512; off <<= 1) {
    int add = (t >= off) ? sd[t - off] : 0;
    __syncthreads();
    sd[t] += add;
    __syncthreads();
  }
  if (t < nb) bsum[t] = sd[t] - v;
  if (t == 0) rowptr[V] = sd[511];
}
__global__ void k_scan3(const int* __restrict__ excl, const int* __restrict__ bsum,
                        int* __restrict__ rowptr, int V) {
  int i = blockIdx.x * 256 + threadIdx.x;
  if (i < V) rowptr[i] = excl[i] + bsum[i >> 8];
}
__global__ void k_scatter(const int* __restrict__ idx, const float* __restrict__ val,
                          const int* __restrict__ rowptr, int* __restrict__ cur,
                          int* __restrict__ ecol, float* __restrict__ eval, int E) {
  int e = blockIdx.x * 256 + threadIdx.x;
  if (e < E) {
    int d = idx[2 * e];
    int p = rowptr[d] + atomicAdd(&cur[d], 1);
    ecol[p] = idx[2 * e + 1];
    eval[p] = val[e];
  }
}
__global__ __launch_bounds__(256)
void k_spmm_csr(const int* __restrict__ rowptr, const int* __restrict__ ecol,
                const float* __restrict__ eval, const float* __restrict__ E,
                u16* __restrict__ GE, int V) {
  int r = blockIdx.x * 8 + (threadIdx.x >> 5);
  int lane = threadIdx.x & 31;
  if (r >= V) return;
  int j1 = rowptr[r + 1];
  float4 a = make_float4(0.f,0.f,0.f,0.f);
  for (int j = rowptr[r]; j < j1; j++) {
    int c = ecol[j];
    float v = eval[j];
    float4 x = ld4(E + (size_t)c * KE + lane * 4);
    a.x = fmaf(v, x.x, a.x); a.y = fmaf(v, x.y, a.y);
    a.z = fmaf(v, x.z, a.z); a.w = fmaf(v, x.w, a.w);
  }
  ushort4 o;
  o.x = f2bf(a.x); o.y = f2bf(a.y); o.z = f2bf(a.z); o.w = f2bf(a.w);
  *(ushort4*)(GE + (size_t)r * KE + lane * 4) = o;
}

// ============================ segment max ============================
__global__ void k_segmax_init(unsigned* __restrict__ u, int n) {
  int i = blockIdx.x * 256 + threadIdx.x;
  if (i < n) u[i] = 0x007FFFFFu;
}
__global__ void k_segmax_scatter(const float* __restrict__ X, const int* __restrict__ tr,
                                 unsigned* __restrict__ u) {
  int i = blockIdx.x * 256 + threadIdx.x;
  if (i >= V3 * C3) return;
  int v = i >> 7, c = i & 127;
  unsigned b = __float_as_uint(X[i]);
  unsigned m = (b & 0x80000000u) ? ~b : (b | 0x80000000u);
  atomicMax(&u[((size_t)tr[v] << 7) + c], m);
}
__global__ void k_segmax_decode(const unsigned* __restrict__ u, float* __restrict__ out, int n) {
  int i = blockIdx.x * 256 + threadIdx.x;
  if (i < n) {
    unsigned m = u[i];
    float f = 0.f;
    if (m != 0x007FFFFFu) {
      unsigned b = (m & 0x80000000u) ? (m & 0x7FFFFFFFu) : ~m;
      f = __uint_as_float(b);
    }
    out[i] = f;
  }
}

// ========================= final projection ==========================
__global__ __launch_bounds__(256)
void k_outproj(const float* __restrict__ Y, const float* __restrict__ W,
               const float* __restrict__ B, float* __restrict__ OUT, int V) {
  __shared__ float Wl[128][22];
  __shared__ float ys[8][128];
  const int tid = threadIdx.x;
  for (int f = tid; f < 128 * 21; f += 256) Wl[f / 21][f % 21] = W[f];
  {
    int r = tid >> 5, cc = (tid & 31) * 4;
    int v = blockIdx.x * 8 + r;
    float4 yv = make_float4(0.f,0.f,0.f,0.f);
    if (v < V) yv = ld4(Y + (size_t)v * C3 + cc);
    st4(&ys[r][cc], yv);
  }
  __syncthreads();
  int r = tid >> 5, c = tid & 31;
  int v = blockIdx.x * 8 + r;
  if (v < V && c < 21) {
    float acc = B[c];
    #pragma unroll 8
    for (int k = 0; k < 128; k++) acc = fmaf(ys[r][k], Wl[k][c], acc);
    OUT[(size_t)v * 21 + c] = acc;
  }
}

// =====================================================================
extern "C" void kernel_launch(void* const* d_in, const int* in_sizes, int n_in,
                              void* d_out, int out_size, void* d_ws, size_t ws_size,
                              hipStream_t stream)
{
  (void)in_sizes; (void)n_in; (void)out_size;
  const float* x_in    = (const float*)d_in[0];
  const float* mass3   = (const float*)d_in[1];
  const float* evals3  = (const float*)d_in[2];
  const float* evecs3  = (const float*)d_in[3];
  const int*   gX3i    = (const int*)d_in[4];
  const float* gX3v    = (const float*)d_in[5];
  const int*   gY3i    = (const int*)d_in[6];
  const float* gY3v    = (const float*)d_in[7];
  const float* massm   = (const float*)d_in[8];
  const float* evalsm  = (const float*)d_in[9];
  const float* evecsm  = (const float*)d_in[10];
  const int*   gXmi    = (const int*)d_in[11];
  const float* gXmv    = (const float*)d_in[12];
  const int*   gYmi    = (const int*)d_in[13];
  const float* gYmv    = (const float*)d_in[14];
  const int*   tr34    = (const int*)d_in[15];
  const float* in_w    = (const float*)d_in[16];
  const float* in_b    = (const float*)d_in[17];
  const float* widen_w = (const float*)d_in[18];
  const float* widen_b = (const float*)d_in[19];
  const float* narrow_w= (const float*)d_in[20];
  const float* narrow_b= (const float*)d_in[21];
  const float* halve_w = (const float*)d_in[22];
  const float* halve_b = (const float*)d_in[23];
  const float* out_w   = (const float*)d_in[24];
  const float* out_b   = (const float*)d_in[25];
  const float* enc_p[9]; const float* mid_p[9]; const float* dec_p[9];
  for (int i = 0; i < 9; i++) {
    enc_p[i] = (const float*)d_in[26 + i];
    mid_p[i] = (const float*)d_in[35 + i];
    dec_p[i] = (const float*)d_in[44 + i];
  }

  // ---------------- workspace layout (~218 MB, proven) ----------------
  char* ws = (char*)d_ws;
  const size_t B3 = (size_t)V3 * C3 * 4;
  size_t off = 0;
  float* SA = (float*)(ws + off); off += B3;
  float* SB = (float*)(ws + off); off += B3;
  u16* GEX3 = (u16*)(ws + off); off += (size_t)V3 * KE * 2;
  u16* GEY3 = (u16*)(ws + off); off += (size_t)V3 * KE * 2;
  u16* GEXm = (u16*)(ws + off); off += (size_t)VM * KE * 2;
  u16* GEYm = (u16*)(ws + off); off += (size_t)VM * KE * 2;
  u16* BSCR = (u16*)(ws + off); off += (size_t)V3 * C3 * 2;
  float* spec = (float*)(ws + off); off += 131072;
  u16* St  = (u16*)(ws + off); off += 65536;
  u16* Trt = (u16*)(ws + off); off += 65536;
  u16* Tit = (u16*)(ws + off); off += 65536;
  u16* SWt = (u16*)(ws + off); off += 65536;
  u16* wT  = (u16*)(ws + off); off += 2400000;
  int* bsum = (int*)(ws + off); off += 4096;
  const size_t NEED = off;
  if (ws_size < NEED) return;

  // CSR scratch overlays SA (dead before in_proj)
  int*   rowptr = (int*)SA;
  int*   deg    = (int*)((char*)SA + 400128);
  int*   ecol   = (int*)((char*)SA + 800256);
  float* evalv  = (float*)((char*)SA + 4000256);

  // mid-phase overlay inside SB (x3 lives in SA then)
  unsigned* xm_u  = (unsigned*)((char*)SB);
  float*    xm_dec= (float*)((char*)SB + 12800000);
  float*    m0    = (float*)((char*)SB + 25600000);
  float*    m1    = (float*)((char*)SB);
  u16* BSCR0 = BSCR;
  u16* BSCR1 = BSCR + (size_t)VM * CMID;

  // weight-transpose suballocation (element offsets)
  u16* in_wt    = wT + 0;
  u16* widen_t  = wT + 2048;
  u16* narrow_t = wT + 34816;
  u16* halve_t  = wT + 67584;
  u16* enc_w0t  = wT + 100352;
  u16* enc_w1t  = wT + 198656;
  u16* enc_w2t  = wT + 231424;
  u16* mid_w0t  = wT + 264192;
  u16* mid_w1t  = wT + 657408;
  u16* mid_w2t  = wT + 788480;
  u16* dec_w0t  = wT + 919552;
  u16* dec_w1t  = wT + 1017856;
  u16* dec_w2t  = wT + 1050624;

  auto prepw = [&](const float* W, u16* WT, int K, int N, int z) {
    k_prepw<<<dim3(cdiv(K * N, 256), 1, z), 256, 0, stream>>>(W, WT, K, N);
  };
  prepw(in_w, in_wt, 16, 128, 1);
  prepw(widen_w, widen_t, 128, 256, 1);
  prepw(narrow_w, narrow_t, 256, 128, 1);
  prepw(halve_w, halve_t, 256, 128, 1);
  prepw(enc_p[3], enc_w0t, 384, 128, 2);
  prepw(enc_p[5], enc_w1t, 128, 128, 2);
  prepw(enc_p[7], enc_w2t, 128, 128, 2);
  prepw(mid_p[3], mid_w0t, 768, 256, 2);
  prepw(mid_p[5], mid_w1t, 256, 256, 2);
  prepw(mid_p[7], mid_w2t, 256, 256, 2);
  prepw(dec_p[3], dec_w0t, 384, 128, 2);
  prepw(dec_p[5], dec_w1t, 128, 128, 2);
  prepw(dec_p[7], dec_w2t, 128, 128, 2);

  auto build_ge = [&](const int* idx, const float* val, int E_, int V_,
                      const float* Evec, u16* GE) {
    hipMemsetAsync(deg, 0, (size_t)V_ * 4, stream);
    k_hist<<<cdiv(E_, 256), 256, 0, stream>>>(idx, deg, E_);
    int nb = cdiv(V_, 256);
    k_scan1<<<nb, 256, 0, stream>>>(deg, ecol, bsum, V_);
    k_scan2<<<1, 512, 0, stream>>>(bsum, nb, rowptr, V_);
    k_scan3<<<nb, 256, 0, stream>>>(ecol, bsum, rowptr, V_);
    hipMemsetAsync(deg, 0, (size_t)V_ * 4, stream);
    k_scatter<<<cdiv(E_, 256), 256, 0, stream>>>(idx, val, rowptr, deg, ecol, evalv, E_);
    k_spmm_csr<<<cdiv(V_, 8), 256, 0, stream>>>(rowptr, ecol, evalv, Evec, GE, V_);
  };
  build_ge(gX3i, gX3v, E3, V3, evecs3, GEX3);
  build_ge(gY3i, gY3v, E3, V3, evecs3, GEY3);
  build_ge(gXmi, gXmv, EM, VM, evecsm, GEXm);
  build_ge(gYmi, gYmv, EM, VM, evecsm, GEYm);

  const int G3  = cdiv(V3, 128);   // 782  (mgemm BM=128)
  const int GM  = cdiv(VM, 128);   // 196
  const int G3g = cdiv(V3, 64);    // 1563 (mgate BM=64)
  const int GMg = cdiv(VM, 64);    // 391

  auto run_block3 = [&](const float* X, float* OX, const float* p[9],
                        const u16* w0t, const u16* w1t, const u16* w2t, int i) {
    const float* dt  = p[0] + (size_t)i * C3;
    const float* Are = p[1] + (size_t)i * C3 * C3;
    const float* Aim = p[2] + (size_t)i * C3 * C3;
    const float* w0  = p[3] + (size_t)i * 3 * C3 * C3;
    const float* b0  = p[4] + (size_t)i * C3;
    const float* b1  = p[6] + (size_t)i * C3;
    const float* b2  = p[8] + (size_t)i * C3;
    const u16* w0ti = w0t + (size_t)i * 3 * C3 * C3;
    const u16* w1ti = w1t + (size_t)i * C3 * C3;
    const u16* w2ti = w2t + (size_t)i * C3 * C3;
    hipMemsetAsync(spec, 0, (size_t)KE * C3 * 4, stream);
    k_specmm<<<dim3(cdiv(V3, 256), 2, 1), 256, 0, stream>>>(evecs3, X, mass3, spec, C3, V3, 256);
    k_smallprep<C3><<<KE, C3, 0, stream>>>(spec, evals3, dt, Are, Aim, w0, St, Trt, Tit, SWt);
    k_mgate<<<dim3(G3g, 1), 256, 0, stream>>>(GEX3, GEY3, St, Trt, Tit, BSCR, C3, V3);
    k_mgemm<true,false,false,true><<<dim3(G3, 1), 256, 0, stream>>>(
        X, 0, C3, w0ti, 3*C3, 0,
        BSCR, 1, C3, w0ti, 3*C3, 2*C3,
        evecs3, 0, KE, SWt, 128, 0,
        nullptr, b0, nullptr, BSCR, C3, V3);
    k_mgemm<true,false,false,true><<<dim3(G3, 1), 256, 0, stream>>>(
        BSCR, 1, C3, w1ti, C3, 0,
        nullptr,0,0,nullptr,0,0, nullptr,0,0,nullptr,0,0,
        nullptr, b1, nullptr, BSCR, C3, V3);
    k_mgemm<false,true,false,false><<<dim3(G3, 1), 256, 0, stream>>>(
        BSCR, 1, C3, w2ti, C3, 0,
        nullptr,0,0,nullptr,0,0, nullptr,0,0,nullptr,0,0,
        nullptr, b2, X, OX, C3, V3);
  };
  auto run_blockm = [&](const float* X, float* OX, const float* p[9],
                        const u16* w0t, const u16* w1t, const u16* w2t, int i) {
    const float* dt  = p[0] + (size_t)i * CMID;
    const float* Are = p[1] + (size_t)i * CMID * CMID;
    const float* Aim = p[2] + (size_t)i * CMID * CMID;
    const float* w0  = p[3] + (size_t)i * 3 * CMID * CMID;
    const float* b0  = p[4] + (size_t)i * CMID;
    const float* b1  = p[6] + (size_t)i * CMID;
    const float* b2  = p[8] + (size_t)i * CMID;
    const u16* w0ti = w0t + (size_t)i * 3 * CMID * CMID;
    const u16* w1ti = w1t + (size_t)i * CMID * CMID;
    const u16* w2ti = w2t + (size_t)i * CMID * CMID;
    hipMemsetAsync(spec, 0, (size_t)KE * CMID * 4, stream);
    k_specmm<<<dim3(cdiv(VM, 128), 2, 2), 256, 0, stream>>>(evecsm, X, massm, spec, CMID, VM, 128);
    k_smallprep<CMID><<<KE, CMID, 0, stream>>>(spec, evalsm, dt, Are, Aim, w0, St, Trt, Tit, SWt);
    k_mgate<<<dim3(GMg, 2), 256, 0, stream>>>(GEXm, GEYm, St, Trt, Tit, BSCR0, CMID, VM);
    k_mgemm<true,false,false,true><<<dim3(GM, 2), 256, 0, stream>>>(
        X, 0, CMID, w0ti, 3*CMID, 0,
        BSCR0, 1, CMID, w0ti, 3*CMID, 2*CMID,
        evecsm, 0, KE, SWt, 128, 0,
        nullptr, b0, nullptr, BSCR1, CMID, VM);
    k_mgemm<true,false,false,true><<<dim3(GM, 2), 256, 0, stream>>>(
        BSCR1, 1, CMID, w1ti, CMID, 0,
        nullptr,0,0,nullptr,0,0, nullptr,0,0,nullptr,0,0,
        nullptr, b1, nullptr, BSCR0, CMID, VM);
    k_mgemm<false,true,false,false><<<dim3(GM, 2), 256, 0, stream>>>(
        BSCR0, 1, CMID, w2ti, CMID, 0,
        nullptr,0,0,nullptr,0,0, nullptr,0,0,nullptr,0,0,
        nullptr, b2, X, OX, CMID, VM);
  };

  // ---- encoder ----
  k_mgemm<true,false,false,false><<<dim3(G3, 1), 256, 0, stream>>>(
      x_in, 0, 16, in_wt, 16, 0,
      nullptr,0,0,nullptr,0,0, nullptr,0,0,nullptr,0,0,
      nullptr, in_b, nullptr, SA, C3, V3);
  run_block3(SA, SB, enc_p, enc_w0t, enc_w1t, enc_w2t, 0);
  run_block3(SB, SA, enc_p, enc_w0t, enc_w1t, enc_w2t, 1);   // x3 = SA

  // ---- pool ----
  k_segmax_init<<<cdiv(VM * C3, 256), 256, 0, stream>>>(xm_u, VM * C3);
  k_segmax_scatter<<<cdiv(V3 * C3, 256), 256, 0, stream>>>(SA, tr34, xm_u);
  k_segmax_decode<<<cdiv(VM * C3, 256), 256, 0, stream>>>(xm_u, xm_dec, VM * C3);
  k_mgemm<true,false,false,false><<<dim3(GM, 2), 256, 0, stream>>>(
      xm_dec, 0, C3, widen_t, C3, 0,
      nullptr,0,0,nullptr,0,0, nullptr,0,0,nullptr,0,0,
      nullptr, widen_b, nullptr, m0, CMID, VM);
  run_blockm(m0, m1, mid_p, mid_w0t, mid_w1t, mid_w2t, 0);
  run_blockm(m1, m0, mid_p, mid_w0t, mid_w1t, mid_w2t, 1);   // m_final = m0

  // ---- unpool ----
  k_mgemm<true,false,true,true><<<dim3(G3, 1), 256, 0, stream>>>(
      m0, 0, CMID, narrow_t, CMID, 0,
      nullptr,0,0,nullptr,0,0, nullptr,0,0,nullptr,0,0,
      tr34, narrow_b, nullptr, BSCR, C3, V3);
  k_mgemm<true,false,false,false><<<dim3(G3, 1), 256, 0, stream>>>(
      BSCR, 1, C3, halve_t, 2*C3, 0,
      SA, 0, C3, halve_t, 2*C3, C3,
      nullptr,0,0,nullptr,0,0,
      nullptr, halve_b, nullptr, SB, C3, V3);

  // ---- decoder ----
  run_block3(SB, SA, dec_p, dec_w0t, dec_w1t, dec_w2t, 0);
  run_block3(SA, SB, dec_p, dec_w0t, dec_w1t, dec_w2t, 1);

  // ---- output projection ----
  k_outproj<<<cdiv(V3, 8), 256, 0, stream>>>(SB, out_w, out_b, (float*)d_out, V3);
}

// Round 5
// 2216.986 us; speedup vs baseline: 1.2563x; 1.2563x over previous
//
#include <hip/hip_runtime.h>
#include <cstdint>
#include <cstddef>

// ---------------- problem constants (fixed by setup_inputs) ----------------
static constexpr int V3   = 100000;
static constexpr int VM   = 25000;
static constexpr int KE   = 128;
static constexpr int E3   = 800000;
static constexpr int EM   = 200000;
static constexpr int C3   = 128;
static constexpr int CMID = 256;

typedef unsigned short u16;
typedef unsigned int   u32;
using short8v = __attribute__((ext_vector_type(8))) short;
using f32x4   = __attribute__((ext_vector_type(4))) float;

#define DEVI __device__ __forceinline__
DEVI float4 ld4(const float* p){ return *(const float4*)p; }
DEVI void   st4(float* p, float4 v){ *(float4*)p = v; }
DEVI float  bf2f(u16 u){ return __uint_as_float(((u32)u) << 16); }
DEVI u16    f2bf(float f){
  u32 u = __float_as_uint(f);
  u += 0x7FFFu + ((u >> 16) & 1u);   // RNE
  return (u16)(u >> 16);
}
DEVI u32 pk2(float a, float b){ return (u32)f2bf(a) | ((u32)f2bf(b) << 16); }
// swizzled LDS tile addressing (rows of 32 u16 = 4 octets, stride 40 u16)
DEVI int lofs(int row, int oct){ return row * 40 + ((oct ^ ((row >> 3) & 3)) << 3); }

static inline int cdiv(int a, int b){ return (a + b - 1) / b; }

// =====================================================================
// MFMA GEMM (round-3 proven structure): BM=64 rows, BN=128 cols, 4 waves.
// OUT[v][:] = act( concat(A0,A1,A2)[v,:] @ W + bias (+res) )
// A sources f32 (aty=0) or bf16 (aty=1); W pre-transposed bf16 Wt[n][k].
// Optional dual-store: f32 OUT + bf16 OUTB shadow.
// In-place over a row-aligned A source / res is safe: block reads only its
// own 64-row stripe before the epilogue writes it (gridDim.y windows write
// disjoint column ranges, so in-place res/OUT is safe for y>1 too).
// =====================================================================
template<bool RELU, bool RES, bool GATHER, bool OBF16>
__global__ __launch_bounds__(256)
void k_mgemm(const void* __restrict__ A0, int aty0, int K0,
             const u16* __restrict__ wt0, int wl0, int wo0,
             const void* __restrict__ A1, int aty1, int K1,
             const u16* __restrict__ wt1, int wl1, int wo1,
             const void* __restrict__ A2, int aty2, int K2,
             const u16* __restrict__ wt2, int wl2, int wo2,
             const int* __restrict__ gidx,
             const float* __restrict__ bias, const float* __restrict__ res,
             void* __restrict__ OUT, u16* __restrict__ OUTB, int CO, int V)
{
  __shared__ __align__(16) u16 As[64 * 40];
  __shared__ __align__(16) u16 Ws[128 * 40];

  const int tid  = threadIdx.x;
  const int wave = tid >> 6, lane = tid & 63;
  const int vbase = blockIdx.x * 64;
  const int ncol0 = blockIdx.y * 128;
  const int KT = K0 + K1 + K2;

  f32x4 acc[8];
  #pragma unroll
  for (int n = 0; n < 8; n++) { acc[n][0]=0.f; acc[n][1]=0.f; acc[n][2]=0.f; acc[n][3]=0.f; }

  const int ar = tid >> 2, ac = tid & 3;
  const int arow = vbase + ar;
  int grow0 = arow;
  if (GATHER && arow < V) grow0 = gidx[arow];

  for (int kt = 0; kt < KT; kt += 32) {
    { // ---- A stage: 64x32 -> bf16 LDS ----
      int kg = kt + ac * 8;
      uint4 aw = make_uint4(0,0,0,0);
      if (arow < V && kg < KT) {
        const void* src; int aty, koff, sK; bool s0;
        if (kg < K0)            { src=A0; aty=aty0; koff=0;     sK=K0; s0=true;  }
        else if (kg < K0 + K1)  { src=A1; aty=aty1; koff=K0;    sK=K1; s0=false; }
        else                    { src=A2; aty=aty2; koff=K0+K1; sK=K2; s0=false; }
        int row = (GATHER && s0) ? grow0 : arow;
        int kl = kg - koff;
        if (aty) {
          aw = *(const uint4*)((const u16*)src + (size_t)row * sK + kl);
        } else {
          const float* fp = (const float*)src + (size_t)row * sK + kl;
          float4 x = ld4(fp), y = ld4(fp + 4);
          aw = make_uint4(pk2(x.x,x.y), pk2(x.z,x.w), pk2(y.x,y.y), pk2(y.z,y.w));
        }
      }
      *(uint4*)&As[ar * 40 + ac * 8] = aw;
    }
    // ---- W stage: 128 cols x 32k ----
    #pragma unroll
    for (int i = 0; i < 2; i++) {
      int col = tid & 127;
      int c = (tid >> 7) + 2 * i;
      int kg = kt + c * 8;
      uint4 ww = make_uint4(0,0,0,0);
      if (kg < KT) {
        const u16* wt; int koff, wl, wo;
        if (kg < K0)           { wt=wt0; koff=0;     wl=wl0; wo=wo0; }
        else if (kg < K0+K1)   { wt=wt1; koff=K0;    wl=wl1; wo=wo1; }
        else                   { wt=wt2; koff=K0+K1; wl=wl2; wo=wo2; }
        ww = *(const uint4*)(wt + (size_t)(ncol0 + col) * wl + wo + (kg - koff));
      }
      *(uint4*)&Ws[col * 40 + c * 8] = ww;
    }
    __syncthreads();
    {
      const int mrow = (wave << 4) + (lane & 15);
      const int kc = lane >> 4;
      short8v a = *(const short8v*)(const void*)&As[mrow * 40 + kc * 8];
      #pragma unroll
      for (int n = 0; n < 8; n++) {
        short8v b = *(const short8v*)(const void*)&Ws[(n * 16 + (lane & 15)) * 40 + kc * 8];
        acc[n] = __builtin_amdgcn_mfma_f32_16x16x32_bf16(a, b, acc[n], 0, 0, 0);
      }
    }
    __syncthreads();
  }

  const int q4 = (lane >> 4) * 4, colb = lane & 15;
  #pragma unroll
  for (int n = 0; n < 8; n++) {
    int gcol = ncol0 + n * 16 + colb;
    float bv = bias ? bias[gcol] : 0.f;
    #pragma unroll
    for (int q = 0; q < 4; q++) {
      int grow = vbase + (wave << 4) + q4 + q;
      if (grow >= V) continue;
      float o = acc[n][q] + bv;
      size_t idx = (size_t)grow * CO + gcol;
      if (RES) o += res[idx];
      if (RELU) o = fmaxf(o, 0.f);
      if (OBF16) ((u16*)OUT)[idx] = f2bf(o);
      else {
        ((float*)OUT)[idx] = o;
        if (OUTB) OUTB[idx] = f2bf(o);
      }
    }
  }
}

// =====================================================================
// MFMA megagate: BM=64 rows, BN=128 cols (blockIdx.y windows for CO=256),
// register prefetch. gx=GEX@S gy=GEY@S br=GEX@Tr-GEY@Ti bi=GEX@Ti+GEY@Tr
// GF = tanh(gx*br+gy*bi) -> bf16.
// =====================================================================
__global__ __launch_bounds__(256)
void k_mgate(const u16* __restrict__ GEX, const u16* __restrict__ GEY,
             const u16* __restrict__ St, const u16* __restrict__ Trt,
             const u16* __restrict__ Tit,
             u16* __restrict__ GF, int CO, int V)
{
  __shared__ __align__(16) u16 Ax[64*40], Ay[64*40], An[64*40];
  __shared__ __align__(16) u16 Bs[128*40], Br_[128*40], Bi_[128*40];

  const int tid = threadIdx.x;
  const int wave = tid >> 6, lane = tid & 63;
  const int vbase = blockIdx.x * 64;
  const int ncol0 = blockIdx.y * 128;

  f32x4 gx[8], gy[8], br[8], bi[8];
  #pragma unroll
  for (int n = 0; n < 8; n++)
    #pragma unroll
    for (int q = 0; q < 4; q++) { gx[n][q]=0.f; gy[n][q]=0.f; br[n][q]=0.f; bi[n][q]=0.f; }

  const int ar = tid >> 2, aoct = tid & 3;
  const int arow = vbase + ar;
  const int wcol = tid & 127, woct0 = (tid >> 7) * 2;

  uint4 zx = make_uint4(0,0,0,0), zy = make_uint4(0,0,0,0);
  if (arow < V) {
    zx = *(const uint4*)(GEX + (size_t)arow * KE + aoct * 8);
    zy = *(const uint4*)(GEY + (size_t)arow * KE + aoct * 8);
  }
  size_t wb = (size_t)(ncol0 + wcol) * KE + woct0 * 8;
  uint4 ps0 = *(const uint4*)(St + wb),  ps1 = *(const uint4*)(St + wb + 8);
  uint4 pr0 = *(const uint4*)(Trt + wb), pr1 = *(const uint4*)(Trt + wb + 8);
  uint4 pi0 = *(const uint4*)(Tit + wb), pi1 = *(const uint4*)(Tit + wb + 8);

  for (int kt = 0; kt < KE; kt += 32) {
    __syncthreads();
    uint4 zn = make_uint4(zy.x ^ 0x80008000u, zy.y ^ 0x80008000u,
                          zy.z ^ 0x80008000u, zy.w ^ 0x80008000u);
    *(uint4*)&Ax[lofs(ar, aoct)] = zx;
    *(uint4*)&Ay[lofs(ar, aoct)] = zy;
    *(uint4*)&An[lofs(ar, aoct)] = zn;
    *(uint4*)&Bs[lofs(wcol, woct0)]      = ps0;
    *(uint4*)&Bs[lofs(wcol, woct0 + 1)]  = ps1;
    *(uint4*)&Br_[lofs(wcol, woct0)]     = pr0;
    *(uint4*)&Br_[lofs(wcol, woct0 + 1)] = pr1;
    *(uint4*)&Bi_[lofs(wcol, woct0)]     = pi0;
    *(uint4*)&Bi_[lofs(wcol, woct0 + 1)] = pi1;
    __syncthreads();
    int kn = kt + 32;
    if (kn < KE) {
      if (arow < V) {
        zx = *(const uint4*)(GEX + (size_t)arow * KE + kn + aoct * 8);
        zy = *(const uint4*)(GEY + (size_t)arow * KE + kn + aoct * 8);
      }
      size_t w2 = (size_t)(ncol0 + wcol) * KE + kn + woct0 * 8;
      ps0 = *(const uint4*)(St + w2);  ps1 = *(const uint4*)(St + w2 + 8);
      pr0 = *(const uint4*)(Trt + w2); pr1 = *(const uint4*)(Trt + w2 + 8);
      pi0 = *(const uint4*)(Tit + w2); pi1 = *(const uint4*)(Tit + w2 + 8);
    }
    const int kc = lane >> 4, ml = lane & 15;
    int mrow = wave * 16 + ml;
    short8v ax = *(const short8v*)(const void*)&Ax[lofs(mrow, kc)];
    short8v ay = *(const short8v*)(const void*)&Ay[lofs(mrow, kc)];
    short8v an = *(const short8v*)(const void*)&An[lofs(mrow, kc)];
    #pragma unroll
    for (int n = 0; n < 8; n++) {
      int bofs = lofs(n * 16 + ml, kc);
      short8v bs  = *(const short8v*)(const void*)&Bs[bofs];
      short8v brv = *(const short8v*)(const void*)&Br_[bofs];
      short8v biv = *(const short8v*)(const void*)&Bi_[bofs];
      gx[n] = __builtin_amdgcn_mfma_f32_16x16x32_bf16(ax, bs,  gx[n], 0,0,0);
      gy[n] = __builtin_amdgcn_mfma_f32_16x16x32_bf16(ay, bs,  gy[n], 0,0,0);
      br[n] = __builtin_amdgcn_mfma_f32_16x16x32_bf16(ax, brv, br[n], 0,0,0);
      br[n] = __builtin_amdgcn_mfma_f32_16x16x32_bf16(an, biv, br[n], 0,0,0);
      bi[n] = __builtin_amdgcn_mfma_f32_16x16x32_bf16(ax, biv, bi[n], 0,0,0);
      bi[n] = __builtin_amdgcn_mfma_f32_16x16x32_bf16(ay, brv, bi[n], 0,0,0);
    }
  }

  const int q4 = (lane >> 4) * 4, colb = lane & 15;
  #pragma unroll
  for (int n = 0; n < 8; n++) {
    int gcol = ncol0 + n * 16 + colb;
    #pragma unroll
    for (int q = 0; q < 4; q++) {
      int grow = vbase + wave * 16 + q4 + q;
      if (grow >= V) continue;
      float o = tanhf(gx[n][q] * br[n][q] + gy[n][q] * bi[n][q]);
      GF[(size_t)grow * CO + gcol] = f2bf(o);
    }
  }
}

// =====================================================================
// MFMA spectral down-projection, bf16 inputs:
// SPEC[ke][c] += sum_v E[v][ke]*X[v][c]*mass[v]; split-K + f32 atomics.
// grid: x=K-chunk, y=m-half(64), z=col-window(128)
// =====================================================================
__global__ __launch_bounds__(256)
void k_specmm(const u16* __restrict__ E, const u16* __restrict__ X,
              const float* __restrict__ mass, float* __restrict__ SPEC,
              int C, int V, int CH)
{
  __shared__ __align__(16) u16 As[64 * 40];
  __shared__ __align__(16) u16 Bs[128 * 40];

  const int tid = threadIdx.x;
  const int wave = tid >> 6, lane = tid & 63;
  const int m0 = blockIdx.y * 64;
  const int n0 = blockIdx.z * 128;
  const int vs = blockIdx.x * CH;
  const int ve = min(V, vs + CH);

  f32x4 acc[8];
  #pragma unroll
  for (int n = 0; n < 8; n++) { acc[n][0]=0.f; acc[n][1]=0.f; acc[n][2]=0.f; acc[n][3]=0.f; }

  const int am = tid & 63, ac = tid >> 6;
  const int bcol = tid & 127, bc0 = (tid >> 7) * 2;

  u16 ea[8]; float fb0[8], fb1[8], fm0[8], fm1[8];
  auto loadA = [&](int kt) {
    #pragma unroll
    for (int j = 0; j < 8; j++) {
      int v = kt + ac * 8 + j;
      ea[j] = (v < ve) ? E[(size_t)v * KE + m0 + am] : (u16)0;
    }
  };
  auto loadB = [&](int kt) {
    #pragma unroll
    for (int j = 0; j < 8; j++) {
      int v0 = kt + bc0 * 8 + j, v1 = v0 + 8;
      fb0[j] = (v0 < ve) ? bf2f(X[(size_t)v0 * C + n0 + bcol]) : 0.f;
      fm0[j] = (v0 < ve) ? mass[v0] : 0.f;
      fb1[j] = (v1 < ve) ? bf2f(X[(size_t)v1 * C + n0 + bcol]) : 0.f;
      fm1[j] = (v1 < ve) ? mass[v1] : 0.f;
    }
  };
  loadA(vs); loadB(vs);

  for (int kt = vs; kt < ve; kt += 32) {
    __syncthreads();
    *(uint4*)&As[lofs(am, ac)] = make_uint4(
        (u32)ea[0] | ((u32)ea[1] << 16), (u32)ea[2] | ((u32)ea[3] << 16),
        (u32)ea[4] | ((u32)ea[5] << 16), (u32)ea[6] | ((u32)ea[7] << 16));
    float t0[8], t1[8];
    #pragma unroll
    for (int j = 0; j < 8; j++) { t0[j] = fb0[j]*fm0[j]; t1[j] = fb1[j]*fm1[j]; }
    *(uint4*)&Bs[lofs(bcol, bc0)] = make_uint4(
        pk2(t0[0],t0[1]), pk2(t0[2],t0[3]), pk2(t0[4],t0[5]), pk2(t0[6],t0[7]));
    *(uint4*)&Bs[lofs(bcol, bc0 + 1)] = make_uint4(
        pk2(t1[0],t1[1]), pk2(t1[2],t1[3]), pk2(t1[4],t1[5]), pk2(t1[6],t1[7]));
    __syncthreads();
    if (kt + 32 < ve) { loadA(kt + 32); loadB(kt + 32); }
    const int kc = lane >> 4, ml = lane & 15;
    short8v a = *(const short8v*)(const void*)&As[lofs(wave * 16 + ml, kc)];
    #pragma unroll
    for (int n = 0; n < 8; n++) {
      short8v b = *(const short8v*)(const void*)&Bs[lofs(n * 16 + ml, kc)];
      acc[n] = __builtin_amdgcn_mfma_f32_16x16x32_bf16(a, b, acc[n], 0, 0, 0);
    }
  }

  const int q4 = (lane >> 4) * 4, colb = lane & 15;
  #pragma unroll
  for (int n = 0; n < 8; n++) {
    int col = n0 + n * 16 + colb;
    #pragma unroll
    for (int q = 0; q < 4; q++) {
      int row = m0 + wave * 16 + q4 + q;
      unsafeAtomicAdd(&SPEC[(size_t)row * C + col], acc[n][q]);
    }
  }
}

// =====================================================================
// smallprep: S = exp(-evals*max(dt,1e-8))*SPEC; outputs bf16 TRANSPOSED
// St/Trt/Tit [CO][128] (Tr=S@Are, Ti=S@Aim) and SWt = (S@w0b)^T [CO][128]
// =====================================================================
template<int C>
__global__ void k_smallprep(const float* __restrict__ SPEC, const float* __restrict__ evals,
                            const float* __restrict__ dt, const float* __restrict__ Are,
                            const float* __restrict__ Aim, const float* __restrict__ w0,
                            u16* __restrict__ St, u16* __restrict__ Trt,
                            u16* __restrict__ Tit, u16* __restrict__ SWt)
{
  __shared__ float sld[C];
  const int k = blockIdx.x;
  const int c = threadIdx.x;
  const float ev = evals[k];
  float s = expf(-ev * fmaxf(dt[c], 1e-8f)) * SPEC[(size_t)k * C + c];
  sld[c] = s;
  St[(size_t)c * 128 + k] = f2bf(s);
  __syncthreads();
  float tr = 0.f, ti = 0.f, sw = 0.f;
  for (int j = 0; j < C; j++) {
    float sj = sld[j];
    tr = fmaf(sj, Are[(size_t)j * C + c], tr);
    ti = fmaf(sj, Aim[(size_t)j * C + c], ti);
    sw = fmaf(sj, w0[(size_t)(C + j) * C + c], sw);
  }
  Trt[(size_t)c * 128 + k] = f2bf(tr);
  Tit[(size_t)c * 128 + k] = f2bf(ti);
  SWt[(size_t)c * 128 + k] = f2bf(sw);
}

// ===== weight pre-transpose f32[K][N] -> bf16 Wt[N][K] (z batches) =====
__global__ void k_prepw(const float* __restrict__ W, u16* __restrict__ WT, int K, int N) {
  size_t zoff = (size_t)blockIdx.z * K * N;
  int i = blockIdx.x * 256 + threadIdx.x;
  if (i < K * N) {
    int k = i / N, n = i % N;
    WT[zoff + (size_t)n * K + k] = f2bf(W[zoff + i]);
  }
}

// ===== f32 -> bf16 elementwise (n % 4 == 0) =====
__global__ void k_cvt(const float* __restrict__ in, u16* __restrict__ out, int n) {
  int i = (blockIdx.x * 256 + threadIdx.x) * 4;
  if (i < n) {
    float4 v = ld4(in + i);
    ushort4 o; o.x = f2bf(v.x); o.y = f2bf(v.y); o.z = f2bf(v.z); o.w = f2bf(v.w);
    *(ushort4*)(out + i) = o;
  }
}

// ============================ CSR build ==============================
__global__ void k_hist(const int* __restrict__ idx, int* __restrict__ deg, int E) {
  int e = blockIdx.x * 256 + threadIdx.x;
  if (e < E) atomicAdd(&deg[idx[2 * e]], 1);
}
__global__ void k_scan1(const int* __restrict__ deg, int* __restrict__ excl,
                        int* __restrict__ bsum, int V) {
  __shared__ int sd[256];
  int t = threadIdx.x;
  int i = blockIdx.x * 256 + t;
  int v = (i < V) ? deg[i] : 0;
  sd[t] = v;
  __syncthreads();
  for (int off = 1; off < 256; off <<= 1) {
    int add = (t >= off) ? sd[t - off] : 0;
    __syncthreads();
    sd[t] += add;
    __syncthreads();
  }
  if (i < V) excl[i] = sd[t] - v;
  if (t == 255) bsum[blockIdx.x] = sd[255];
}
__global__ void k_scan2(int* __restrict__ bsum, int nb, int* __restrict__ rowptr, int V) {
  __shared__ int sd[512];
  int t = threadIdx.x;
  int v = (t < nb) ? bsum[t] : 0;
  sd[t] = v;
  __syncthreads();
  for (int off = 1; off < 512; off <<= 1) {
    int add = (t >= off) ? sd[t - off] : 0;
    __syncthreads();
    sd[t] += add;
    __syncthreads();
  }
  if (t < nb) bsum[t] = sd[t] - v;
  if (t == 0) rowptr[V] = sd[511];
}
__global__ void k_scan3(const int* __restrict__ excl, const int* __restrict__ bsum,
                        int* __restrict__ rowptr, int V) {
  int i = blockIdx.x * 256 + threadIdx.x;
  if (i < V) rowptr[i] = excl[i] + bsum[i >> 8];
}
__global__ void k_scatter(const int* __restrict__ idx, const float* __restrict__ val,
                          const int* __restrict__ rowptr, int* __restrict__ cur,
                          int* __restrict__ ecol, float* __restrict__ eval, int E) {
  int e = blockIdx.x * 256 + threadIdx.x;
  if (e < E) {
    int d = idx[2 * e];
    int p = rowptr[d] + atomicAdd(&cur[d], 1);
    ecol[p] = idx[2 * e + 1];
    eval[p] = val[e];
  }
}
__global__ __launch_bounds__(256)
void k_spmm_csr(const int* __restrict__ rowptr, const int* __restrict__ ecol,
                const float* __restrict__ eval, const float* __restrict__ E,
                u16* __restrict__ GE, int V) {
  int r = blockIdx.x * 8 + (threadIdx.x >> 5);
  int lane = threadIdx.x & 31;
  if (r >= V) return;
  int j1 = rowptr[r + 1];
  float4 a = make_float4(0.f,0.f,0.f,0.f);
  for (int j = rowptr[r]; j < j1; j++) {
    int c = ecol[j];
    float v = eval[j];
    float4 x = ld4(E + (size_t)c * KE + lane * 4);
    a.x = fmaf(v, x.x, a.x); a.y = fmaf(v, x.y, a.y);
    a.z = fmaf(v, x.z, a.z); a.w = fmaf(v, x.w, a.w);
  }
  ushort4 o;
  o.x = f2bf(a.x); o.y = f2bf(a.y); o.z = f2bf(a.z); o.w = f2bf(a.w);
  *(ushort4*)(GE + (size_t)r * KE + lane * 4) = o;
}

// ============================ segment max ============================
__global__ void k_segmax_init(unsigned* __restrict__ u, int n) {
  int i = blockIdx.x * 256 + threadIdx.x;
  if (i < n) u[i] = 0x007FFFFFu;
}
__global__ void k_segmax_scatter(const float* __restrict__ X, const int* __restrict__ tr,
                                 unsigned* __restrict__ u) {
  int i = blockIdx.x * 256 + threadIdx.x;
  if (i >= V3 * C3) return;
  int v = i >> 7, c = i & 127;
  unsigned b = __float_as_uint(X[i]);
  unsigned m = (b & 0x80000000u) ? ~b : (b | 0x80000000u);
  atomicMax(&u[((size_t)tr[v] << 7) + c], m);
}
__global__ void k_segmax_decode(const unsigned* __restrict__ u, float* __restrict__ out, int n) {
  int i = blockIdx.x * 256 + threadIdx.x;
  if (i < n) {
    unsigned m = u[i];
    float f = 0.f;
    if (m != 0x007FFFFFu) {
      unsigned b = (m & 0x80000000u) ? (m & 0x7FFFFFFFu) : ~m;
      f = __uint_as_float(b);
    }
    out[i] = f;
  }
}

// ========================= final projection ==========================
__global__ __launch_bounds__(256)
void k_outproj(const float* __restrict__ Y, const float* __restrict__ W,
               const float* __restrict__ B, float* __restrict__ OUT, int V) {
  __shared__ float Wl[128][22];
  __shared__ float ys[8][128];
  const int tid = threadIdx.x;
  for (int f = tid; f < 128 * 21; f += 256) Wl[f / 21][f % 21] = W[f];
  {
    int r = tid >> 5, cc = (tid & 31) * 4;
    int v = blockIdx.x * 8 + r;
    float4 yv = make_float4(0.f,0.f,0.f,0.f);
    if (v < V) yv = ld4(Y + (size_t)v * C3 + cc);
    st4(&ys[r][cc], yv);
  }
  __syncthreads();
  int r = tid >> 5, c = tid & 31;
  int v = blockIdx.x * 8 + r;
  if (v < V && c < 21) {
    float acc = B[c];
    #pragma unroll 8
    for (int k = 0; k < 128; k++) acc = fmaf(ys[r][k], Wl[k][c], acc);
    OUT[(size_t)v * 21 + c] = acc;
  }
}

// =====================================================================
extern "C" void kernel_launch(void* const* d_in, const int* in_sizes, int n_in,
                              void* d_out, int out_size, void* d_ws, size_t ws_size,
                              hipStream_t stream)
{
  (void)in_sizes; (void)n_in; (void)out_size;
  const float* x_in    = (const float*)d_in[0];
  const float* mass3   = (const float*)d_in[1];
  const float* evals3  = (const float*)d_in[2];
  const float* evecs3  = (const float*)d_in[3];
  const int*   gX3i    = (const int*)d_in[4];
  const float* gX3v    = (const float*)d_in[5];
  const int*   gY3i    = (const int*)d_in[6];
  const float* gY3v    = (const float*)d_in[7];
  const float* massm   = (const float*)d_in[8];
  const float* evalsm  = (const float*)d_in[9];
  const float* evecsm  = (const float*)d_in[10];
  const int*   gXmi    = (const int*)d_in[11];
  const float* gXmv    = (const float*)d_in[12];
  const int*   gYmi    = (const int*)d_in[13];
  const float* gYmv    = (const float*)d_in[14];
  const int*   tr34    = (const int*)d_in[15];
  const float* in_w    = (const float*)d_in[16];
  const float* in_b    = (const float*)d_in[17];
  const float* widen_w = (const float*)d_in[18];
  const float* widen_b = (const float*)d_in[19];
  const float* narrow_w= (const float*)d_in[20];
  const float* narrow_b= (const float*)d_in[21];
  const float* halve_w = (const float*)d_in[22];
  const float* halve_b = (const float*)d_in[23];
  const float* out_w   = (const float*)d_in[24];
  const float* out_b   = (const float*)d_in[25];
  const float* enc_p[9]; const float* mid_p[9]; const float* dec_p[9];
  for (int i = 0; i < 9; i++) {
    enc_p[i] = (const float*)d_in[26 + i];
    mid_p[i] = (const float*)d_in[35 + i];
    dec_p[i] = (const float*)d_in[44 + i];
  }

  // ---------------- workspace layout (~214 MB, fits proven >=218.1) ----------------
  char* ws = (char*)d_ws;
  size_t off = 0;
  float* XM  = (float*)(ws + off); off += (size_t)V3 * C3 * 4;    // f32 residual master
  u16* SHB   = (u16*)(ws + off);   off += (size_t)V3 * C3 * 2;    // bf16 shadow of XM
  u16* GEX3  = (u16*)(ws + off);   off += (size_t)V3 * KE * 2;
  u16* GEY3  = (u16*)(ws + off);   off += (size_t)V3 * KE * 2;
  u16* GEXm  = (u16*)(ws + off);   off += (size_t)VM * KE * 2;
  u16* GEYm  = (u16*)(ws + off);   off += (size_t)VM * KE * 2;
  u16* BSCR  = (u16*)(ws + off);   off += (size_t)V3 * C3 * 2;    // bf16 scratch gf/h1/h2
  char* E3R  = (char*)(ws + off);  off += (size_t)V3 * KE * 2;    // E3bf; M0 overlay in mid
  u16* Embf  = (u16*)(ws + off);   off += (size_t)VM * KE * 2;
  u16* SHM   = (u16*)(ws + off);   off += (size_t)VM * CMID * 2;  // bf16 shadow of M0
  float* spec= (float*)(ws + off); off += 131072;
  u16* St  = (u16*)(ws + off); off += 65536;
  u16* Trt = (u16*)(ws + off); off += 65536;
  u16* Tit = (u16*)(ws + off); off += 65536;
  u16* SWt = (u16*)(ws + off); off += 65536;
  u16* wT  = (u16*)(ws + off); off += 2400000;
  const size_t NEED = off;
  if (ws_size < NEED) return;

  u16*   E3bf = (u16*)E3R;
  float* M0   = (float*)E3R;                         // VM*256 f32 = same 25.6 MB (mid only)
  // CSR scratch overlays BSCR (dead before first gate)
  int*   rowptr = (int*)BSCR;
  int*   deg    = (int*)((char*)BSCR + 400128);
  int*   ecol   = (int*)((char*)BSCR + 800256);
  float* evalv  = (float*)((char*)BSCR + 4000256);
  int*   bsum   = (int*)((char*)BSCR + 7200256);
  // pool overlays BSCR (dead between blocks)
  unsigned* xm_u  = (unsigned*)BSCR;                 // VM*128 u32 = 12.8 MB
  float*    xm_dec= (float*)((char*)BSCR + 12800000);// VM*128 f32 = 12.8 MB
  u16* BSCR0 = BSCR;
  u16* BSCR1 = BSCR + (size_t)VM * CMID;

  // weight-transpose suballocation (element offsets)
  u16* in_wt    = wT + 0;
  u16* widen_t  = wT + 2048;
  u16* narrow_t = wT + 34816;
  u16* halve_t  = wT + 67584;
  u16* enc_w0t  = wT + 100352;
  u16* enc_w1t  = wT + 198656;
  u16* enc_w2t  = wT + 231424;
  u16* mid_w0t  = wT + 264192;
  u16* mid_w1t  = wT + 657408;
  u16* mid_w2t  = wT + 788480;
  u16* dec_w0t  = wT + 919552;
  u16* dec_w1t  = wT + 1017856;
  u16* dec_w2t  = wT + 1050624;

  auto prepw = [&](const float* W, u16* WT, int K, int N, int z) {
    k_prepw<<<dim3(cdiv(K * N, 256), 1, z), 256, 0, stream>>>(W, WT, K, N);
  };
  prepw(in_w, in_wt, 16, 128, 1);
  prepw(widen_w, widen_t, 128, 256, 1);
  prepw(narrow_w, narrow_t, 256, 128, 1);
  prepw(halve_w, halve_t, 256, 128, 1);
  prepw(enc_p[3], enc_w0t, 384, 128, 2);
  prepw(enc_p[5], enc_w1t, 128, 128, 2);
  prepw(enc_p[7], enc_w2t, 128, 128, 2);
  prepw(mid_p[3], mid_w0t, 768, 256, 2);
  prepw(mid_p[5], mid_w1t, 256, 256, 2);
  prepw(mid_p[7], mid_w2t, 256, 256, 2);
  prepw(dec_p[3], dec_w0t, 384, 128, 2);
  prepw(dec_p[5], dec_w1t, 128, 128, 2);
  prepw(dec_p[7], dec_w2t, 128, 128, 2);

  auto build_ge = [&](const int* idx, const float* val, int E_, int V_,
                      const float* Evec, u16* GE) {
    hipMemsetAsync(deg, 0, (size_t)V_ * 4, stream);
    k_hist<<<cdiv(E_, 256), 256, 0, stream>>>(idx, deg, E_);
    int nb = cdiv(V_, 256);
    k_scan1<<<nb, 256, 0, stream>>>(deg, ecol, bsum, V_);
    k_scan2<<<1, 512, 0, stream>>>(bsum, nb, rowptr, V_);
    k_scan3<<<nb, 256, 0, stream>>>(ecol, bsum, rowptr, V_);
    hipMemsetAsync(deg, 0, (size_t)V_ * 4, stream);
    k_scatter<<<cdiv(E_, 256), 256, 0, stream>>>(idx, val, rowptr, deg, ecol, evalv, E_);
    k_spmm_csr<<<cdiv(V_, 8), 256, 0, stream>>>(rowptr, ecol, evalv, Evec, GE, V_);
  };
  build_ge(gX3i, gX3v, E3, V3, evecs3, GEX3);
  build_ge(gY3i, gY3v, E3, V3, evecs3, GEY3);
  build_ge(gXmi, gXmv, EM, VM, evecsm, GEXm);
  build_ge(gYmi, gYmv, EM, VM, evecsm, GEYm);

  // evecs -> bf16 (after CSR builds since they share no space; E3bf region is its own)
  k_cvt<<<cdiv(V3 * KE / 4, 256), 256, 0, stream>>>(evecs3, E3bf, V3 * KE);
  k_cvt<<<cdiv(VM * KE / 4, 256), 256, 0, stream>>>(evecsm, Embf, VM * KE);

  const int G3 = cdiv(V3, 64);   // 1563
  const int GM = cdiv(VM, 64);   // 391

  // ---- block3: X master XM + shadow SHB, updated in place ----
  auto run_block3 = [&](const float* p[9],
                        const u16* w0t, const u16* w1t, const u16* w2t, int i) {
    const float* dt  = p[0] + (size_t)i * C3;
    const float* Are = p[1] + (size_t)i * C3 * C3;
    const float* Aim = p[2] + (size_t)i * C3 * C3;
    const float* w0  = p[3] + (size_t)i * 3 * C3 * C3;
    const float* b0  = p[4] + (size_t)i * C3;
    const float* b1  = p[6] + (size_t)i * C3;
    const float* b2  = p[8] + (size_t)i * C3;
    const u16* w0ti = w0t + (size_t)i * 3 * C3 * C3;
    const u16* w1ti = w1t + (size_t)i * C3 * C3;
    const u16* w2ti = w2t + (size_t)i * C3 * C3;
    hipMemsetAsync(spec, 0, (size_t)KE * C3 * 4, stream);
    k_specmm<<<dim3(cdiv(V3, 256), 2, 1), 256, 0, stream>>>(E3bf, SHB, mass3, spec, C3, V3, 256);
    k_smallprep<C3><<<KE, C3, 0, stream>>>(spec, evals3, dt, Are, Aim, w0, St, Trt, Tit, SWt);
    k_mgate<<<dim3(G3, 1), 256, 0, stream>>>(GEX3, GEY3, St, Trt, Tit, BSCR, C3, V3);
    k_mgemm<true,false,false,true><<<dim3(G3, 1), 256, 0, stream>>>(
        SHB, 1, C3, w0ti, 3*C3, 0,
        BSCR, 1, C3, w0ti, 3*C3, 2*C3,
        E3bf, 1, KE, SWt, 128, 0,
        nullptr, b0, nullptr, BSCR, nullptr, C3, V3);        // h1 in place over gf
    k_mgemm<true,false,false,true><<<dim3(G3, 1), 256, 0, stream>>>(
        BSCR, 1, C3, w1ti, C3, 0,
        nullptr,0,0,nullptr,0,0, nullptr,0,0,nullptr,0,0,
        nullptr, b1, nullptr, BSCR, nullptr, C3, V3);        // h2 in place
    k_mgemm<false,true,false,false><<<dim3(G3, 1), 256, 0, stream>>>(
        BSCR, 1, C3, w2ti, C3, 0,
        nullptr,0,0,nullptr,0,0, nullptr,0,0,nullptr,0,0,
        nullptr, b2, XM, XM, SHB, C3, V3);                   // residual in place + shadow
  };
  // ---- blockm: M0 master + SHM shadow ----
  auto run_blockm = [&](const float* p[9],
                        const u16* w0t, const u16* w1t, const u16* w2t, int i) {
    const float* dt  = p[0] + (size_t)i * CMID;
    const float* Are = p[1] + (size_t)i * CMID * CMID;
    const float* Aim = p[2] + (size_t)i * CMID * CMID;
    const float* w0  = p[3] + (size_t)i * 3 * CMID * CMID;
    const float* b0  = p[4] + (size_t)i * CMID;
    const float* b1  = p[6] + (size_t)i * CMID;
    const float* b2  = p[8] + (size_t)i * CMID;
    const u16* w0ti = w0t + (size_t)i * 3 * CMID * CMID;
    const u16* w1ti = w1t + (size_t)i * CMID * CMID;
    const u16* w2ti = w2t + (size_t)i * CMID * CMID;
    hipMemsetAsync(spec, 0, (size_t)KE * CMID * 4, stream);
    k_specmm<<<dim3(cdiv(VM, 128), 2, 2), 256, 0, stream>>>(Embf, SHM, massm, spec, CMID, VM, 128);
    k_smallprep<CMID><<<KE, CMID, 0, stream>>>(spec, evalsm, dt, Are, Aim, w0, St, Trt, Tit, SWt);
    k_mgate<<<dim3(GM, 2), 256, 0, stream>>>(GEXm, GEYm, St, Trt, Tit, BSCR0, CMID, VM);
    k_mgemm<true,false,false,true><<<dim3(GM, 2), 256, 0, stream>>>(
        SHM, 1, CMID, w0ti, 3*CMID, 0,
        BSCR0, 1, CMID, w0ti, 3*CMID, 2*CMID,
        Embf, 1, KE, SWt, 128, 0,
        nullptr, b0, nullptr, BSCR1, nullptr, CMID, VM);
    k_mgemm<true,false,false,true><<<dim3(GM, 2), 256, 0, stream>>>(
        BSCR1, 1, CMID, w1ti, CMID, 0,
        nullptr,0,0,nullptr,0,0, nullptr,0,0,nullptr,0,0,
        nullptr, b1, nullptr, BSCR0, nullptr, CMID, VM);
    k_mgemm<false,true,false,false><<<dim3(GM, 2), 256, 0, stream>>>(
        BSCR0, 1, CMID, w2ti, CMID, 0,
        nullptr,0,0,nullptr,0,0, nullptr,0,0,nullptr,0,0,
        nullptr, b2, M0, M0, SHM, CMID, VM);                 // in place + shadow
  };

  // ---- encoder ----
  k_mgemm<true,false,false,false><<<dim3(G3, 1), 256, 0, stream>>>(
      x_in, 0, 16, in_wt, 16, 0,
      nullptr,0,0,nullptr,0,0, nullptr,0,0,nullptr,0,0,
      nullptr, in_b, nullptr, XM, SHB, C3, V3);
  run_block3(enc_p, enc_w0t, enc_w1t, enc_w2t, 0);
  run_block3(enc_p, enc_w0t, enc_w1t, enc_w2t, 1);           // x3 = XM, shadow SHB

  // ---- pool (xm_u/xm_dec overlay BSCR) ----
  k_segmax_init<<<cdiv(VM * C3, 256), 256, 0, stream>>>(xm_u, VM * C3);
  k_segmax_scatter<<<cdiv(V3 * C3, 256), 256, 0, stream>>>(XM, tr34, xm_u);
  k_segmax_decode<<<cdiv(VM * C3, 256), 256, 0, stream>>>(xm_u, xm_dec, VM * C3);
  k_mgemm<true,false,false,false><<<dim3(GM, 2), 256, 0, stream>>>(
      xm_dec, 0, C3, widen_t, C3, 0,
      nullptr,0,0,nullptr,0,0, nullptr,0,0,nullptr,0,0,
      nullptr, widen_b, nullptr, M0, SHM, CMID, VM);         // M0 overlays E3bf (dead in mid)
  run_blockm(mid_p, mid_w0t, mid_w1t, mid_w2t, 0);
  run_blockm(mid_p, mid_w0t, mid_w1t, mid_w2t, 1);           // m_final shadow = SHM

  // ---- unpool: gather+narrow (reads SHM) -> BSCR; halve (BSCR + x3 shadow) -> XM ----
  k_mgemm<true,false,true,true><<<dim3(G3, 1), 256, 0, stream>>>(
      SHM, 1, CMID, narrow_t, CMID, 0,
      nullptr,0,0,nullptr,0,0, nullptr,0,0,nullptr,0,0,
      tr34, narrow_b, nullptr, BSCR, nullptr, C3, V3);
  k_mgemm<true,false,false,false><<<dim3(G3, 1), 256, 0, stream>>>(
      BSCR, 1, C3, halve_t, 2*C3, 0,
      SHB, 1, C3, halve_t, 2*C3, C3,
      nullptr,0,0,nullptr,0,0,
      nullptr, halve_b, nullptr, XM, SHB, C3, V3);           // new stream in place

  // ---- decoder (must rebuild E3bf: it was clobbered by M0 overlay) ----
  k_cvt<<<cdiv(V3 * KE / 4, 256), 256, 0, stream>>>(evecs3, E3bf, V3 * KE);
  run_block3(dec_p, dec_w0t, dec_w1t, dec_w2t, 0);
  run_block3(dec_p, dec_w0t, dec_w1t, dec_w2t, 1);

  // ---- output projection ----
  k_outproj<<<cdiv(V3, 8), 256, 0, stream>>>(XM, out_w, out_b, (float*)d_out, V3);
}

// Round 6
// 2176.313 us; speedup vs baseline: 1.2798x; 1.0187x over previous
//
#include <hip/hip_runtime.h>
#include <cstdint>
#include <cstddef>

// ---------------- problem constants (fixed by setup_inputs) ----------------
static constexpr int V3   = 100000;
static constexpr int VM   = 25000;
static constexpr int KE   = 128;
static constexpr int E3   = 800000;
static constexpr int EM   = 200000;
static constexpr int C3   = 128;
static constexpr int CMID = 256;

typedef unsigned short u16;
typedef unsigned int   u32;
using short8v = __attribute__((ext_vector_type(8))) short;
using f32x4   = __attribute__((ext_vector_type(4))) float;
using f32x16  = __attribute__((ext_vector_type(16))) float;

#define DEVI __device__ __forceinline__
DEVI float4 ld4(const float* p){ return *(const float4*)p; }
DEVI void   st4(float* p, float4 v){ *(float4*)p = v; }
DEVI float  bf2f(u16 u){ return __uint_as_float(((u32)u) << 16); }
DEVI u16    f2bf(float f){
  u32 u = __float_as_uint(f);
  u += 0x7FFFu + ((u >> 16) & 1u);   // RNE
  return (u16)(u >> 16);
}
DEVI u32 pk2(float a, float b){ return (u32)f2bf(a) | ((u32)f2bf(b) << 16); }
DEVI short8v as8(uint4 v){ union { uint4 u; short8v s; } c; c.u = v; return c.s; }
// swizzled LDS tile addressing (rows of 32 u16 = 4 octets, stride 40 u16)
DEVI int lofs(int row, int oct){ return row * 40 + ((oct ^ ((row >> 3) & 3)) << 3); }

static inline int cdiv(int a, int b){ return (a + b - 1) / b; }

// =====================================================================
// MFMA GEMM (proven structure): BM=64 rows, BN=128 cols, 4 waves.
// OUT[v][:] = act( concat(A0,A1,A2)[v,:] @ W + bias (+res) )
// A sources f32 (aty=0) or bf16 (aty=1); W pre-transposed bf16 Wt[n][k].
// Optional dual-store: f32 OUT + bf16 OUTB shadow.
// =====================================================================
template<bool RELU, bool RES, bool GATHER, bool OBF16>
__global__ __launch_bounds__(256)
void k_mgemm(const void* __restrict__ A0, int aty0, int K0,
             const u16* __restrict__ wt0, int wl0, int wo0,
             const void* __restrict__ A1, int aty1, int K1,
             const u16* __restrict__ wt1, int wl1, int wo1,
             const void* __restrict__ A2, int aty2, int K2,
             const u16* __restrict__ wt2, int wl2, int wo2,
             const int* __restrict__ gidx,
             const float* __restrict__ bias, const float* __restrict__ res,
             void* __restrict__ OUT, u16* __restrict__ OUTB, int CO, int V)
{
  __shared__ __align__(16) u16 As[64 * 40];
  __shared__ __align__(16) u16 Ws[128 * 40];

  const int tid  = threadIdx.x;
  const int wave = tid >> 6, lane = tid & 63;
  const int vbase = blockIdx.x * 64;
  const int ncol0 = blockIdx.y * 128;
  const int KT = K0 + K1 + K2;

  f32x4 acc[8];
  #pragma unroll
  for (int n = 0; n < 8; n++) { acc[n][0]=0.f; acc[n][1]=0.f; acc[n][2]=0.f; acc[n][3]=0.f; }

  const int ar = tid >> 2, ac = tid & 3;
  const int arow = vbase + ar;
  int grow0 = arow;
  if (GATHER && arow < V) grow0 = gidx[arow];

  for (int kt = 0; kt < KT; kt += 32) {
    { // ---- A stage: 64x32 -> bf16 LDS ----
      int kg = kt + ac * 8;
      uint4 aw = make_uint4(0,0,0,0);
      if (arow < V && kg < KT) {
        const void* src; int aty, koff, sK; bool s0;
        if (kg < K0)            { src=A0; aty=aty0; koff=0;     sK=K0; s0=true;  }
        else if (kg < K0 + K1)  { src=A1; aty=aty1; koff=K0;    sK=K1; s0=false; }
        else                    { src=A2; aty=aty2; koff=K0+K1; sK=K2; s0=false; }
        int row = (GATHER && s0) ? grow0 : arow;
        int kl = kg - koff;
        if (aty) {
          aw = *(const uint4*)((const u16*)src + (size_t)row * sK + kl);
        } else {
          const float* fp = (const float*)src + (size_t)row * sK + kl;
          float4 x = ld4(fp), y = ld4(fp + 4);
          aw = make_uint4(pk2(x.x,x.y), pk2(x.z,x.w), pk2(y.x,y.y), pk2(y.z,y.w));
        }
      }
      *(uint4*)&As[ar * 40 + ac * 8] = aw;
    }
    // ---- W stage: 128 cols x 32k ----
    #pragma unroll
    for (int i = 0; i < 2; i++) {
      int col = tid & 127;
      int c = (tid >> 7) + 2 * i;
      int kg = kt + c * 8;
      uint4 ww = make_uint4(0,0,0,0);
      if (kg < KT) {
        const u16* wt; int koff, wl, wo;
        if (kg < K0)           { wt=wt0; koff=0;     wl=wl0; wo=wo0; }
        else if (kg < K0+K1)   { wt=wt1; koff=K0;    wl=wl1; wo=wo1; }
        else                   { wt=wt2; koff=K0+K1; wl=wl2; wo=wo2; }
        ww = *(const uint4*)(wt + (size_t)(ncol0 + col) * wl + wo + (kg - koff));
      }
      *(uint4*)&Ws[col * 40 + c * 8] = ww;
    }
    __syncthreads();
    {
      const int mrow = (wave << 4) + (lane & 15);
      const int kc = lane >> 4;
      short8v a = *(const short8v*)(const void*)&As[mrow * 40 + kc * 8];
      #pragma unroll
      for (int n = 0; n < 8; n++) {
        short8v b = *(const short8v*)(const void*)&Ws[(n * 16 + (lane & 15)) * 40 + kc * 8];
        acc[n] = __builtin_amdgcn_mfma_f32_16x16x32_bf16(a, b, acc[n], 0, 0, 0);
      }
    }
    __syncthreads();
  }

  const int q4 = (lane >> 4) * 4, colb = lane & 15;
  #pragma unroll
  for (int n = 0; n < 8; n++) {
    int gcol = ncol0 + n * 16 + colb;
    float bv = bias ? bias[gcol] : 0.f;
    #pragma unroll
    for (int q = 0; q < 4; q++) {
      int grow = vbase + (wave << 4) + q4 + q;
      if (grow >= V) continue;
      float o = acc[n][q] + bv;
      size_t idx = (size_t)grow * CO + gcol;
      if (RES) o += res[idx];
      if (RELU) o = fmaxf(o, 0.f);
      if (OBF16) ((u16*)OUT)[idx] = f2bf(o);
      else {
        ((float*)OUT)[idx] = o;
        if (OUTB) OUTB[idx] = f2bf(o);
      }
    }
  }
}

// =====================================================================
// Register-resident MFMA megagate (no LDS, no barriers).
// Each wave owns 32 rows: GEX/GEY/-GEY held in registers (A-fragments of
// mfma_f32_32x32x16_bf16, 8 k-steps). B (S/Tr/Ti) pre-packed in exact
// B-fragment order -> coalesced 16B/lane streams from L2.
// gx=GEX@S gy=GEY@S br=GEX@Tr-GEY@Ti bi=GEX@Ti+GEY@Tr
// GF = tanh(gx*br+gy*bi) -> bf16.  128 rows/block (4 waves).
// =====================================================================
__global__ __launch_bounds__(256)
void k_mgate_reg(const u16* __restrict__ GEX, const u16* __restrict__ GEY,
                 const u16* __restrict__ pS, const u16* __restrict__ pR,
                 const u16* __restrict__ pI,
                 u16* __restrict__ GF, int CO, int V)
{
  const int lane = threadIdx.x & 63;
  const int wave = threadIdx.x >> 6;
  const int rbase = blockIdx.x * 128 + wave * 32;
  const int arow = rbase + (lane & 31);
  const int koff = (lane >> 5) * 8;
  const bool rok = arow < V;

  uint4 ax[8], ay[8], an[8];
  #pragma unroll
  for (int kt = 0; kt < 8; kt++) {
    uint4 zx = make_uint4(0,0,0,0), zy = make_uint4(0,0,0,0);
    if (rok) {
      zx = *(const uint4*)(GEX + (size_t)arow * KE + kt * 16 + koff);
      zy = *(const uint4*)(GEY + (size_t)arow * KE + kt * 16 + koff);
    }
    ax[kt] = zx; ay[kt] = zy;
    an[kt] = make_uint4(zy.x ^ 0x80008000u, zy.y ^ 0x80008000u,
                        zy.z ^ 0x80008000u, zy.w ^ 0x80008000u);
  }

  const int ngr = CO >> 5;
  for (int g = 0; g < ngr; g++) {
    f32x16 gx, gy, br, bi;
    #pragma unroll
    for (int r = 0; r < 16; r++) { gx[r]=0.f; gy[r]=0.f; br[r]=0.f; bi[r]=0.f; }
    #pragma unroll
    for (int kt = 0; kt < 8; kt++) {
      size_t bo = ((size_t)(g * 8 + kt) * 64 + lane) * 8;
      short8v bs  = *(const short8v*)(const void*)(pS + bo);
      short8v brv = *(const short8v*)(const void*)(pR + bo);
      short8v biv = *(const short8v*)(const void*)(pI + bo);
      short8v axv = as8(ax[kt]), ayv = as8(ay[kt]), anv = as8(an[kt]);
      gx = __builtin_amdgcn_mfma_f32_32x32x16_bf16(axv, bs,  gx, 0, 0, 0);
      gy = __builtin_amdgcn_mfma_f32_32x32x16_bf16(ayv, bs,  gy, 0, 0, 0);
      br = __builtin_amdgcn_mfma_f32_32x32x16_bf16(axv, brv, br, 0, 0, 0);
      br = __builtin_amdgcn_mfma_f32_32x32x16_bf16(anv, biv, br, 0, 0, 0);
      bi = __builtin_amdgcn_mfma_f32_32x32x16_bf16(axv, biv, bi, 0, 0, 0);
      bi = __builtin_amdgcn_mfma_f32_32x32x16_bf16(ayv, brv, bi, 0, 0, 0);
    }
    const int col = g * 32 + (lane & 31);
    const int rhi = 4 * (lane >> 5);
    #pragma unroll
    for (int r = 0; r < 16; r++) {
      int row = rbase + (r & 3) + 8 * (r >> 2) + rhi;
      if (row < V) {
        float o = tanhf(gx[r] * br[r] + gy[r] * bi[r]);
        GF[(size_t)row * CO + col] = f2bf(o);
      }
    }
  }
}

// =====================================================================
// MFMA spectral down-projection, bf16 inputs:
// SPEC[ke][c] += sum_v E[v][ke]*X[v][c]*mass[v]; split-K + f32 atomics.
// grid: x=K-chunk, y=m-half(64), z=col-window(128)
// =====================================================================
__global__ __launch_bounds__(256)
void k_specmm(const u16* __restrict__ E, const u16* __restrict__ X,
              const float* __restrict__ mass, float* __restrict__ SPEC,
              int C, int V, int CH)
{
  __shared__ __align__(16) u16 As[64 * 40];
  __shared__ __align__(16) u16 Bs[128 * 40];

  const int tid = threadIdx.x;
  const int wave = tid >> 6, lane = tid & 63;
  const int m0 = blockIdx.y * 64;
  const int n0 = blockIdx.z * 128;
  const int vs = blockIdx.x * CH;
  const int ve = min(V, vs + CH);

  f32x4 acc[8];
  #pragma unroll
  for (int n = 0; n < 8; n++) { acc[n][0]=0.f; acc[n][1]=0.f; acc[n][2]=0.f; acc[n][3]=0.f; }

  const int am = tid & 63, ac = tid >> 6;
  const int bcol = tid & 127, bc0 = (tid >> 7) * 2;

  u16 ea[8]; float fb0[8], fb1[8], fm0[8], fm1[8];
  auto loadA = [&](int kt) {
    #pragma unroll
    for (int j = 0; j < 8; j++) {
      int v = kt + ac * 8 + j;
      ea[j] = (v < ve) ? E[(size_t)v * KE + m0 + am] : (u16)0;
    }
  };
  auto loadB = [&](int kt) {
    #pragma unroll
    for (int j = 0; j < 8; j++) {
      int v0 = kt + bc0 * 8 + j, v1 = v0 + 8;
      fb0[j] = (v0 < ve) ? bf2f(X[(size_t)v0 * C + n0 + bcol]) : 0.f;
      fm0[j] = (v0 < ve) ? mass[v0] : 0.f;
      fb1[j] = (v1 < ve) ? bf2f(X[(size_t)v1 * C + n0 + bcol]) : 0.f;
      fm1[j] = (v1 < ve) ? mass[v1] : 0.f;
    }
  };
  loadA(vs); loadB(vs);

  for (int kt = vs; kt < ve; kt += 32) {
    __syncthreads();
    *(uint4*)&As[lofs(am, ac)] = make_uint4(
        (u32)ea[0] | ((u32)ea[1] << 16), (u32)ea[2] | ((u32)ea[3] << 16),
        (u32)ea[4] | ((u32)ea[5] << 16), (u32)ea[6] | ((u32)ea[7] << 16));
    float t0[8], t1[8];
    #pragma unroll
    for (int j = 0; j < 8; j++) { t0[j] = fb0[j]*fm0[j]; t1[j] = fb1[j]*fm1[j]; }
    *(uint4*)&Bs[lofs(bcol, bc0)] = make_uint4(
        pk2(t0[0],t0[1]), pk2(t0[2],t0[3]), pk2(t0[4],t0[5]), pk2(t0[6],t0[7]));
    *(uint4*)&Bs[lofs(bcol, bc0 + 1)] = make_uint4(
        pk2(t1[0],t1[1]), pk2(t1[2],t1[3]), pk2(t1[4],t1[5]), pk2(t1[6],t1[7]));
    __syncthreads();
    if (kt + 32 < ve) { loadA(kt + 32); loadB(kt + 32); }
    const int kc = lane >> 4, ml = lane & 15;
    short8v a = *(const short8v*)(const void*)&As[lofs(wave * 16 + ml, kc)];
    #pragma unroll
    for (int n = 0; n < 8; n++) {
      short8v b = *(const short8v*)(const void*)&Bs[lofs(n * 16 + ml, kc)];
      acc[n] = __builtin_amdgcn_mfma_f32_16x16x32_bf16(a, b, acc[n], 0, 0, 0);
    }
  }

  const int q4 = (lane >> 4) * 4, colb = lane & 15;
  #pragma unroll
  for (int n = 0; n < 8; n++) {
    int col = n0 + n * 16 + colb;
    #pragma unroll
    for (int q = 0; q < 4; q++) {
      int row = m0 + wave * 16 + q4 + q;
      unsafeAtomicAdd(&SPEC[(size_t)row * C + col], acc[n][q]);
    }
  }
}

// =====================================================================
// smallprep: S = exp(-evals*max(dt,1e-8))*SPEC; emits S/Tr/Ti PACKED in
// MFMA-B-fragment order (pS/pR/pI) and SWt = (S@w0b)^T [CO][128] bf16.
// packed index for element (k, c):
//   g=c>>5, kt=k>>4, hi=(k>>3)&1, j=k&7, lane=(c&31)+32*hi
//   pidx = ((g*8+kt)*64 + lane)*8 + j
// =====================================================================
template<int C>
__global__ void k_smallprep(const float* __restrict__ SPEC, const float* __restrict__ evals,
                            const float* __restrict__ dt, const float* __restrict__ Are,
                            const float* __restrict__ Aim, const float* __restrict__ w0,
                            u16* __restrict__ pS, u16* __restrict__ pR,
                            u16* __restrict__ pI, u16* __restrict__ SWt)
{
  __shared__ float sld[C];
  const int k = blockIdx.x;
  const int c = threadIdx.x;
  const float ev = evals[k];
  float s = expf(-ev * fmaxf(dt[c], 1e-8f)) * SPEC[(size_t)k * C + c];
  sld[c] = s;
  const size_t pidx = ((size_t)((c >> 5) * 8 + (k >> 4)) * 64
                       + (c & 31) + ((k >> 3) & 1) * 32) * 8 + (k & 7);
  pS[pidx] = f2bf(s);
  __syncthreads();
  float tr = 0.f, ti = 0.f, sw = 0.f;
  for (int j = 0; j < C; j++) {
    float sj = sld[j];
    tr = fmaf(sj, Are[(size_t)j * C + c], tr);
    ti = fmaf(sj, Aim[(size_t)j * C + c], ti);
    sw = fmaf(sj, w0[(size_t)(C + j) * C + c], sw);
  }
  pR[pidx] = f2bf(tr);
  pI[pidx] = f2bf(ti);
  SWt[(size_t)c * 128 + k] = f2bf(sw);
}

// ===== weight pre-transpose f32[K][N] -> bf16 Wt[N][K] (z batches) =====
__global__ void k_prepw(const float* __restrict__ W, u16* __restrict__ WT, int K, int N) {
  size_t zoff = (size_t)blockIdx.z * K * N;
  int i = blockIdx.x * 256 + threadIdx.x;
  if (i < K * N) {
    int k = i / N, n = i % N;
    WT[zoff + (size_t)n * K + k] = f2bf(W[zoff + i]);
  }
}

// ===== f32 -> bf16 elementwise (n % 4 == 0) =====
__global__ void k_cvt(const float* __restrict__ in, u16* __restrict__ out, int n) {
  int i = (blockIdx.x * 256 + threadIdx.x) * 4;
  if (i < n) {
    float4 v = ld4(in + i);
    ushort4 o; o.x = f2bf(v.x); o.y = f2bf(v.y); o.z = f2bf(v.z); o.w = f2bf(v.w);
    *(ushort4*)(out + i) = o;
  }
}

// ============================ CSR build ==============================
__global__ void k_hist(const int* __restrict__ idx, int* __restrict__ deg, int E) {
  int e = blockIdx.x * 256 + threadIdx.x;
  if (e < E) atomicAdd(&deg[idx[2 * e]], 1);
}
__global__ void k_scan1(const int* __restrict__ deg, int* __restrict__ excl,
                        int* __restrict__ bsum, int V) {
  __shared__ int sd[256];
  int t = threadIdx.x;
  int i = blockIdx.x * 256 + t;
  int v = (i < V) ? deg[i] : 0;
  sd[t] = v;
  __syncthreads();
  for (int off = 1; off < 256; off <<= 1) {
    int add = (t >= off) ? sd[t - off] : 0;
    __syncthreads();
    sd[t] += add;
    __syncthreads();
  }
  if (i < V) excl[i] = sd[t] - v;
  if (t == 255) bsum[blockIdx.x] = sd[255];
}
__global__ void k_scan2(int* __restrict__ bsum, int nb, int* __restrict__ rowptr, int V) {
  __shared__ int sd[512];
  int t = threadIdx.x;
  int v = (t < nb) ? bsum[t] : 0;
  sd[t] = v;
  __syncthreads();
  for (int off = 1; off < 512; off <<= 1) {
    int add = (t >= off) ? sd[t - off] : 0;
    __syncthreads();
    sd[t] += add;
    __syncthreads();
  }
  if (t < nb) bsum[t] = sd[t] - v;
  if (t == 0) rowptr[V] = sd[511];
}
__global__ void k_scan3(const int* __restrict__ excl, const int* __restrict__ bsum,
                        int* __restrict__ rowptr, int V) {
  int i = blockIdx.x * 256 + threadIdx.x;
  if (i < V) rowptr[i] = excl[i] + bsum[i >> 8];
}
__global__ void k_scatter(const int* __restrict__ idx, const float* __restrict__ val,
                          const int* __restrict__ rowptr, int* __restrict__ cur,
                          int* __restrict__ ecol, float* __restrict__ eval, int E) {
  int e = blockIdx.x * 256 + threadIdx.x;
  if (e < E) {
    int d = idx[2 * e];
    int p = rowptr[d] + atomicAdd(&cur[d], 1);
    ecol[p] = idx[2 * e + 1];
    eval[p] = val[e];
  }
}
__global__ __launch_bounds__(256)
void k_spmm_csr(const int* __restrict__ rowptr, const int* __restrict__ ecol,
                const float* __restrict__ eval, const float* __restrict__ E,
                u16* __restrict__ GE, int V) {
  int r = blockIdx.x * 8 + (threadIdx.x >> 5);
  int lane = threadIdx.x & 31;
  if (r >= V) return;
  int j1 = rowptr[r + 1];
  float4 a = make_float4(0.f,0.f,0.f,0.f);
  for (int j = rowptr[r]; j < j1; j++) {
    int c = ecol[j];
    float v = eval[j];
    float4 x = ld4(E + (size_t)c * KE + lane * 4);
    a.x = fmaf(v, x.x, a.x); a.y = fmaf(v, x.y, a.y);
    a.z = fmaf(v, x.z, a.z); a.w = fmaf(v, x.w, a.w);
  }
  ushort4 o;
  o.x = f2bf(a.x); o.y = f2bf(a.y); o.z = f2bf(a.z); o.w = f2bf(a.w);
  *(ushort4*)(GE + (size_t)r * KE + lane * 4) = o;
}

// ============================ segment max ============================
__global__ void k_segmax_init(unsigned* __restrict__ u, int n) {
  int i = blockIdx.x * 256 + threadIdx.x;
  if (i < n) u[i] = 0x007FFFFFu;
}
__global__ void k_segmax_scatter(const float* __restrict__ X, const int* __restrict__ tr,
                                 unsigned* __restrict__ u) {
  int i = blockIdx.x * 256 + threadIdx.x;
  if (i >= V3 * C3) return;
  int v = i >> 7, c = i & 127;
  unsigned b = __float_as_uint(X[i]);
  unsigned m = (b & 0x80000000u) ? ~b : (b | 0x80000000u);
  atomicMax(&u[((size_t)tr[v] << 7) + c], m);
}
__global__ void k_segmax_decode(const unsigned* __restrict__ u, float* __restrict__ out, int n) {
  int i = blockIdx.x * 256 + threadIdx.x;
  if (i < n) {
    unsigned m = u[i];
    float f = 0.f;
    if (m != 0x007FFFFFu) {
      unsigned b = (m & 0x80000000u) ? (m & 0x7FFFFFFFu) : ~m;
      f = __uint_as_float(b);
    }
    out[i] = f;
  }
}

// ========================= final projection ==========================
__global__ __launch_bounds__(256)
void k_outproj(const float* __restrict__ Y, const float* __restrict__ W,
               const float* __restrict__ B, float* __restrict__ OUT, int V) {
  __shared__ float Wl[128][22];
  __shared__ float ys[8][128];
  const int tid = threadIdx.x;
  for (int f = tid; f < 128 * 21; f += 256) Wl[f / 21][f % 21] = W[f];
  {
    int r = tid >> 5, cc = (tid & 31) * 4;
    int v = blockIdx.x * 8 + r;
    float4 yv = make_float4(0.f,0.f,0.f,0.f);
    if (v < V) yv = ld4(Y + (size_t)v * C3 + cc);
    st4(&ys[r][cc], yv);
  }
  __syncthreads();
  int r = tid >> 5, c = tid & 31;
  int v = blockIdx.x * 8 + r;
  if (v < V && c < 21) {
    float acc = B[c];
    #pragma unroll 8
    for (int k = 0; k < 128; k++) acc = fmaf(ys[r][k], Wl[k][c], acc);
    OUT[(size_t)v * 21 + c] = acc;
  }
}

// =====================================================================
extern "C" void kernel_launch(void* const* d_in, const int* in_sizes, int n_in,
                              void* d_out, int out_size, void* d_ws, size_t ws_size,
                              hipStream_t stream)
{
  (void)in_sizes; (void)n_in; (void)out_size;
  const float* x_in    = (const float*)d_in[0];
  const float* mass3   = (const float*)d_in[1];
  const float* evals3  = (const float*)d_in[2];
  const float* evecs3  = (const float*)d_in[3];
  const int*   gX3i    = (const int*)d_in[4];
  const float* gX3v    = (const float*)d_in[5];
  const int*   gY3i    = (const int*)d_in[6];
  const float* gY3v    = (const float*)d_in[7];
  const float* massm   = (const float*)d_in[8];
  const float* evalsm  = (const float*)d_in[9];
  const float* evecsm  = (const float*)d_in[10];
  const int*   gXmi    = (const int*)d_in[11];
  const float* gXmv    = (const float*)d_in[12];
  const int*   gYmi    = (const int*)d_in[13];
  const float* gYmv    = (const float*)d_in[14];
  const int*   tr34    = (const int*)d_in[15];
  const float* in_w    = (const float*)d_in[16];
  const float* in_b    = (const float*)d_in[17];
  const float* widen_w = (const float*)d_in[18];
  const float* widen_b = (const float*)d_in[19];
  const float* narrow_w= (const float*)d_in[20];
  const float* narrow_b= (const float*)d_in[21];
  const float* halve_w = (const float*)d_in[22];
  const float* halve_b = (const float*)d_in[23];
  const float* out_w   = (const float*)d_in[24];
  const float* out_b   = (const float*)d_in[25];
  const float* enc_p[9]; const float* mid_p[9]; const float* dec_p[9];
  for (int i = 0; i < 9; i++) {
    enc_p[i] = (const float*)d_in[26 + i];
    mid_p[i] = (const float*)d_in[35 + i];
    dec_p[i] = (const float*)d_in[44 + i];
  }

  // ---------------- workspace layout (~214 MB, fits proven >=218.1) ----------------
  char* ws = (char*)d_ws;
  size_t off = 0;
  float* XM  = (float*)(ws + off); off += (size_t)V3 * C3 * 4;    // f32 residual master
  u16* SHB   = (u16*)(ws + off);   off += (size_t)V3 * C3 * 2;    // bf16 shadow of XM
  u16* GEX3  = (u16*)(ws + off);   off += (size_t)V3 * KE * 2;
  u16* GEY3  = (u16*)(ws + off);   off += (size_t)V3 * KE * 2;
  u16* GEXm  = (u16*)(ws + off);   off += (size_t)VM * KE * 2;
  u16* GEYm  = (u16*)(ws + off);   off += (size_t)VM * KE * 2;
  u16* BSCR  = (u16*)(ws + off);   off += (size_t)V3 * C3 * 2;    // bf16 scratch gf/h1/h2
  char* E3R  = (char*)(ws + off);  off += (size_t)V3 * KE * 2;    // E3bf; M0 overlay in mid
  u16* Embf  = (u16*)(ws + off);   off += (size_t)VM * KE * 2;
  u16* SHM   = (u16*)(ws + off);   off += (size_t)VM * CMID * 2;  // bf16 shadow of M0
  float* spec= (float*)(ws + off); off += 131072;
  u16* pS  = (u16*)(ws + off); off += 65536;
  u16* pR  = (u16*)(ws + off); off += 65536;
  u16* pI  = (u16*)(ws + off); off += 65536;
  u16* SWt = (u16*)(ws + off); off += 65536;
  u16* wT  = (u16*)(ws + off); off += 2400000;
  const size_t NEED = off;
  if (ws_size < NEED) return;

  u16*   E3bf = (u16*)E3R;
  float* M0   = (float*)E3R;                         // VM*256 f32 = same 25.6 MB (mid only)
  // CSR scratch overlays BSCR (dead before first gate)
  int*   rowptr = (int*)BSCR;
  int*   deg    = (int*)((char*)BSCR + 400128);
  int*   ecol   = (int*)((char*)BSCR + 800256);
  float* evalv  = (float*)((char*)BSCR + 4000256);
  int*   bsum   = (int*)((char*)BSCR + 7200256);
  // pool overlays BSCR (dead between blocks)
  unsigned* xm_u  = (unsigned*)BSCR;                 // VM*128 u32 = 12.8 MB
  float*    xm_dec= (float*)((char*)BSCR + 12800000);// VM*128 f32 = 12.8 MB
  u16* BSCR0 = BSCR;
  u16* BSCR1 = BSCR + (size_t)VM * CMID;

  // weight-transpose suballocation (element offsets)
  u16* in_wt    = wT + 0;
  u16* widen_t  = wT + 2048;
  u16* narrow_t = wT + 34816;
  u16* halve_t  = wT + 67584;
  u16* enc_w0t  = wT + 100352;
  u16* enc_w1t  = wT + 198656;
  u16* enc_w2t  = wT + 231424;
  u16* mid_w0t  = wT + 264192;
  u16* mid_w1t  = wT + 657408;
  u16* mid_w2t  = wT + 788480;
  u16* dec_w0t  = wT + 919552;
  u16* dec_w1t  = wT + 1017856;
  u16* dec_w2t  = wT + 1050624;

  auto prepw = [&](const float* W, u16* WT, int K, int N, int z) {
    k_prepw<<<dim3(cdiv(K * N, 256), 1, z), 256, 0, stream>>>(W, WT, K, N);
  };
  prepw(in_w, in_wt, 16, 128, 1);
  prepw(widen_w, widen_t, 128, 256, 1);
  prepw(narrow_w, narrow_t, 256, 128, 1);
  prepw(halve_w, halve_t, 256, 128, 1);
  prepw(enc_p[3], enc_w0t, 384, 128, 2);
  prepw(enc_p[5], enc_w1t, 128, 128, 2);
  prepw(enc_p[7], enc_w2t, 128, 128, 2);
  prepw(mid_p[3], mid_w0t, 768, 256, 2);
  prepw(mid_p[5], mid_w1t, 256, 256, 2);
  prepw(mid_p[7], mid_w2t, 256, 256, 2);
  prepw(dec_p[3], dec_w0t, 384, 128, 2);
  prepw(dec_p[5], dec_w1t, 128, 128, 2);
  prepw(dec_p[7], dec_w2t, 128, 128, 2);

  auto build_ge = [&](const int* idx, const float* val, int E_, int V_,
                      const float* Evec, u16* GE) {
    hipMemsetAsync(deg, 0, (size_t)V_ * 4, stream);
    k_hist<<<cdiv(E_, 256), 256, 0, stream>>>(idx, deg, E_);
    int nb = cdiv(V_, 256);
    k_scan1<<<nb, 256, 0, stream>>>(deg, ecol, bsum, V_);
    k_scan2<<<1, 512, 0, stream>>>(bsum, nb, rowptr, V_);
    k_scan3<<<nb, 256, 0, stream>>>(ecol, bsum, rowptr, V_);
    hipMemsetAsync(deg, 0, (size_t)V_ * 4, stream);
    k_scatter<<<cdiv(E_, 256), 256, 0, stream>>>(idx, val, rowptr, deg, ecol, evalv, E_);
    k_spmm_csr<<<cdiv(V_, 8), 256, 0, stream>>>(rowptr, ecol, evalv, Evec, GE, V_);
  };
  build_ge(gX3i, gX3v, E3, V3, evecs3, GEX3);
  build_ge(gY3i, gY3v, E3, V3, evecs3, GEY3);
  build_ge(gXmi, gXmv, EM, VM, evecsm, GEXm);
  build_ge(gYmi, gYmv, EM, VM, evecsm, GEYm);

  // evecs -> bf16
  k_cvt<<<cdiv(V3 * KE / 4, 256), 256, 0, stream>>>(evecs3, E3bf, V3 * KE);
  k_cvt<<<cdiv(VM * KE / 4, 256), 256, 0, stream>>>(evecsm, Embf, VM * KE);

  const int G3 = cdiv(V3, 64);   // 1563
  const int GM = cdiv(VM, 64);   // 391

  // ---- block3: X master XM + shadow SHB, updated in place ----
  auto run_block3 = [&](const float* p[9],
                        const u16* w0t, const u16* w1t, const u16* w2t, int i) {
    const float* dt  = p[0] + (size_t)i * C3;
    const float* Are = p[1] + (size_t)i * C3 * C3;
    const float* Aim = p[2] + (size_t)i * C3 * C3;
    const float* w0  = p[3] + (size_t)i * 3 * C3 * C3;
    const float* b0  = p[4] + (size_t)i * C3;
    const float* b1  = p[6] + (size_t)i * C3;
    const float* b2  = p[8] + (size_t)i * C3;
    const u16* w0ti = w0t + (size_t)i * 3 * C3 * C3;
    const u16* w1ti = w1t + (size_t)i * C3 * C3;
    const u16* w2ti = w2t + (size_t)i * C3 * C3;
    hipMemsetAsync(spec, 0, (size_t)KE * C3 * 4, stream);
    k_specmm<<<dim3(cdiv(V3, 256), 2, 1), 256, 0, stream>>>(E3bf, SHB, mass3, spec, C3, V3, 256);
    k_smallprep<C3><<<KE, C3, 0, stream>>>(spec, evals3, dt, Are, Aim, w0, pS, pR, pI, SWt);
    k_mgate_reg<<<cdiv(V3, 128), 256, 0, stream>>>(GEX3, GEY3, pS, pR, pI, BSCR, C3, V3);
    k_mgemm<true,false,false,true><<<dim3(G3, 1), 256, 0, stream>>>(
        SHB, 1, C3, w0ti, 3*C3, 0,
        BSCR, 1, C3, w0ti, 3*C3, 2*C3,
        E3bf, 1, KE, SWt, 128, 0,
        nullptr, b0, nullptr, BSCR, nullptr, C3, V3);        // h1 in place over gf
    k_mgemm<true,false,false,true><<<dim3(G3, 1), 256, 0, stream>>>(
        BSCR, 1, C3, w1ti, C3, 0,
        nullptr,0,0,nullptr,0,0, nullptr,0,0,nullptr,0,0,
        nullptr, b1, nullptr, BSCR, nullptr, C3, V3);        // h2 in place
    k_mgemm<false,true,false,false><<<dim3(G3, 1), 256, 0, stream>>>(
        BSCR, 1, C3, w2ti, C3, 0,
        nullptr,0,0,nullptr,0,0, nullptr,0,0,nullptr,0,0,
        nullptr, b2, XM, XM, SHB, C3, V3);                   // residual in place + shadow
  };
  // ---- blockm: M0 master + SHM shadow ----
  auto run_blockm = [&](const float* p[9],
                        const u16* w0t, const u16* w1t, const u16* w2t, int i) {
    const float* dt  = p[0] + (size_t)i * CMID;
    const float* Are = p[1] + (size_t)i * CMID * CMID;
    const float* Aim = p[2] + (size_t)i * CMID * CMID;
    const float* w0  = p[3] + (size_t)i * 3 * CMID * CMID;
    const float* b0  = p[4] + (size_t)i * CMID;
    const float* b1  = p[6] + (size_t)i * CMID;
    const float* b2  = p[8] + (size_t)i * CMID;
    const u16* w0ti = w0t + (size_t)i * 3 * CMID * CMID;
    const u16* w1ti = w1t + (size_t)i * CMID * CMID;
    const u16* w2ti = w2t + (size_t)i * CMID * CMID;
    hipMemsetAsync(spec, 0, (size_t)KE * CMID * 4, stream);
    k_specmm<<<dim3(cdiv(VM, 128), 2, 2), 256, 0, stream>>>(Embf, SHM, massm, spec, CMID, VM, 128);
    k_smallprep<CMID><<<KE, CMID, 0, stream>>>(spec, evalsm, dt, Are, Aim, w0, pS, pR, pI, SWt);
    k_mgate_reg<<<cdiv(VM, 128), 256, 0, stream>>>(GEXm, GEYm, pS, pR, pI, BSCR0, CMID, VM);
    k_mgemm<true,false,false,true><<<dim3(GM, 2), 256, 0, stream>>>(
        SHM, 1, CMID, w0ti, 3*CMID, 0,
        BSCR0, 1, CMID, w0ti, 3*CMID, 2*CMID,
        Embf, 1, KE, SWt, 128, 0,
        nullptr, b0, nullptr, BSCR1, nullptr, CMID, VM);
    k_mgemm<true,false,false,true><<<dim3(GM, 2), 256, 0, stream>>>(
        BSCR1, 1, CMID, w1ti, CMID, 0,
        nullptr,0,0,nullptr,0,0, nullptr,0,0,nullptr,0,0,
        nullptr, b1, nullptr, BSCR0, nullptr, CMID, VM);
    k_mgemm<false,true,false,false><<<dim3(GM, 2), 256, 0, stream>>>(
        BSCR0, 1, CMID, w2ti, CMID, 0,
        nullptr,0,0,nullptr,0,0, nullptr,0,0,nullptr,0,0,
        nullptr, b2, M0, M0, SHM, CMID, VM);                 // in place + shadow
  };

  // ---- encoder ----
  k_mgemm<true,false,false,false><<<dim3(G3, 1), 256, 0, stream>>>(
      x_in, 0, 16, in_wt, 16, 0,
      nullptr,0,0,nullptr,0,0, nullptr,0,0,nullptr,0,0,
      nullptr, in_b, nullptr, XM, SHB, C3, V3);
  run_block3(enc_p, enc_w0t, enc_w1t, enc_w2t, 0);
  run_block3(enc_p, enc_w0t, enc_w1t, enc_w2t, 1);           // x3 = XM, shadow SHB

  // ---- pool (xm_u/xm_dec overlay BSCR) ----
  k_segmax_init<<<cdiv(VM * C3, 256), 256, 0, stream>>>(xm_u, VM * C3);
  k_segmax_scatter<<<cdiv(V3 * C3, 256), 256, 0, stream>>>(XM, tr34, xm_u);
  k_segmax_decode<<<cdiv(VM * C3, 256), 256, 0, stream>>>(xm_u, xm_dec, VM * C3);
  k_mgemm<true,false,false,false><<<dim3(GM, 2), 256, 0, stream>>>(
      xm_dec, 0, C3, widen_t, C3, 0,
      nullptr,0,0,nullptr,0,0, nullptr,0,0,nullptr,0,0,
      nullptr, widen_b, nullptr, M0, SHM, CMID, VM);         // M0 overlays E3bf (dead in mid)
  run_blockm(mid_p, mid_w0t, mid_w1t, mid_w2t, 0);
  run_blockm(mid_p, mid_w0t, mid_w1t, mid_w2t, 1);           // m_final shadow = SHM

  // ---- unpool: gather+narrow (reads SHM) -> BSCR; halve -> XM ----
  k_mgemm<true,false,true,true><<<dim3(G3, 1), 256, 0, stream>>>(
      SHM, 1, CMID, narrow_t, CMID, 0,
      nullptr,0,0,nullptr,0,0, nullptr,0,0,nullptr,0,0,
      tr34, narrow_b, nullptr, BSCR, nullptr, C3, V3);
  k_mgemm<true,false,false,false><<<dim3(G3, 1), 256, 0, stream>>>(
      BSCR, 1, C3, halve_t, 2*C3, 0,
      SHB, 1, C3, halve_t, 2*C3, C3,
      nullptr,0,0,nullptr,0,0,
      nullptr, halve_b, nullptr, XM, SHB, C3, V3);           // new stream in place

  // ---- decoder (rebuild E3bf: clobbered by M0 overlay) ----
  k_cvt<<<cdiv(V3 * KE / 4, 256), 256, 0, stream>>>(evecs3, E3bf, V3 * KE);
  run_block3(dec_p, dec_w0t, dec_w1t, dec_w2t, 0);
  run_block3(dec_p, dec_w0t, dec_w1t, dec_w2t, 1);

  // ---- output projection ----
  k_outproj<<<cdiv(V3, 8), 256, 0, stream>>>(XM, out_w, out_b, (float*)d_out, V3);
}

// Round 7
// 1956.685 us; speedup vs baseline: 1.4235x; 1.1122x over previous
//
#include <hip/hip_runtime.h>
#include <cstdint>
#include <cstddef>

// ---------------- problem constants (fixed by setup_inputs) ----------------
static constexpr int V3   = 100000;
static constexpr int VM   = 25000;
static constexpr int KE   = 128;
static constexpr int E3   = 800000;
static constexpr int EM   = 200000;
static constexpr int C3   = 128;
static constexpr int CMID = 256;

typedef unsigned short u16;
typedef unsigned int   u32;
using short8v = __attribute__((ext_vector_type(8))) short;
using f32x4   = __attribute__((ext_vector_type(4))) float;
using f32x16  = __attribute__((ext_vector_type(16))) float;

#define DEVI __device__ __forceinline__
DEVI float4 ld4(const float* p){ return *(const float4*)p; }
DEVI void   st4(float* p, float4 v){ *(float4*)p = v; }
DEVI float  bf2f(u16 u){ return __uint_as_float(((u32)u) << 16); }
DEVI u16    f2bf(float f){
  u32 u = __float_as_uint(f);
  u += 0x7FFFu + ((u >> 16) & 1u);   // RNE
  return (u16)(u >> 16);
}
DEVI u32 pk2(float a, float b){ return (u32)f2bf(a) | ((u32)f2bf(b) << 16); }
DEVI short8v as8(uint4 v){ union { uint4 u; short8v s; } c; c.u = v; return c.s; }
// swizzled LDS tile addressing (rows of 32 u16 = 4 octets, stride 40 u16)
DEVI int lofs(int row, int oct){ return row * 40 + ((oct ^ ((row >> 3) & 3)) << 3); }

static inline int cdiv(int a, int b){ return (a + b - 1) / b; }

// =====================================================================
// MFMA GEMM (proven structure): BM=64 rows, BN=128 cols, 4 waves.
// =====================================================================
template<bool RELU, bool RES, bool GATHER, bool OBF16>
__global__ __launch_bounds__(256)
void k_mgemm(const void* __restrict__ A0, int aty0, int K0,
             const u16* __restrict__ wt0, int wl0, int wo0,
             const void* __restrict__ A1, int aty1, int K1,
             const u16* __restrict__ wt1, int wl1, int wo1,
             const void* __restrict__ A2, int aty2, int K2,
             const u16* __restrict__ wt2, int wl2, int wo2,
             const int* __restrict__ gidx,
             const float* __restrict__ bias, const float* __restrict__ res,
             void* __restrict__ OUT, u16* __restrict__ OUTB, int CO, int V)
{
  __shared__ __align__(16) u16 As[64 * 40];
  __shared__ __align__(16) u16 Ws[128 * 40];

  const int tid  = threadIdx.x;
  const int wave = tid >> 6, lane = tid & 63;
  const int vbase = blockIdx.x * 64;
  const int ncol0 = blockIdx.y * 128;
  const int KT = K0 + K1 + K2;

  f32x4 acc[8];
  #pragma unroll
  for (int n = 0; n < 8; n++) { acc[n][0]=0.f; acc[n][1]=0.f; acc[n][2]=0.f; acc[n][3]=0.f; }

  const int ar = tid >> 2, ac = tid & 3;
  const int arow = vbase + ar;
  int grow0 = arow;
  if (GATHER && arow < V) grow0 = gidx[arow];

  for (int kt = 0; kt < KT; kt += 32) {
    { // A stage
      int kg = kt + ac * 8;
      uint4 aw = make_uint4(0,0,0,0);
      if (arow < V && kg < KT) {
        const void* src; int aty, koff, sK; bool s0;
        if (kg < K0)            { src=A0; aty=aty0; koff=0;     sK=K0; s0=true;  }
        else if (kg < K0 + K1)  { src=A1; aty=aty1; koff=K0;    sK=K1; s0=false; }
        else                    { src=A2; aty=aty2; koff=K0+K1; sK=K2; s0=false; }
        int row = (GATHER && s0) ? grow0 : arow;
        int kl = kg - koff;
        if (aty) {
          aw = *(const uint4*)((const u16*)src + (size_t)row * sK + kl);
        } else {
          const float* fp = (const float*)src + (size_t)row * sK + kl;
          float4 x = ld4(fp), y = ld4(fp + 4);
          aw = make_uint4(pk2(x.x,x.y), pk2(x.z,x.w), pk2(y.x,y.y), pk2(y.z,y.w));
        }
      }
      *(uint4*)&As[ar * 40 + ac * 8] = aw;
    }
    #pragma unroll
    for (int i = 0; i < 2; i++) { // W stage
      int col = tid & 127;
      int c = (tid >> 7) + 2 * i;
      int kg = kt + c * 8;
      uint4 ww = make_uint4(0,0,0,0);
      if (kg < KT) {
        const u16* wt; int koff, wl, wo;
        if (kg < K0)           { wt=wt0; koff=0;     wl=wl0; wo=wo0; }
        else if (kg < K0+K1)   { wt=wt1; koff=K0;    wl=wl1; wo=wo1; }
        else                   { wt=wt2; koff=K0+K1; wl=wl2; wo=wo2; }
        ww = *(const uint4*)(wt + (size_t)(ncol0 + col) * wl + wo + (kg - koff));
      }
      *(uint4*)&Ws[col * 40 + c * 8] = ww;
    }
    __syncthreads();
    {
      const int mrow = (wave << 4) + (lane & 15);
      const int kc = lane >> 4;
      short8v a = *(const short8v*)(const void*)&As[mrow * 40 + kc * 8];
      #pragma unroll
      for (int n = 0; n < 8; n++) {
        short8v b = *(const short8v*)(const void*)&Ws[(n * 16 + (lane & 15)) * 40 + kc * 8];
        acc[n] = __builtin_amdgcn_mfma_f32_16x16x32_bf16(a, b, acc[n], 0, 0, 0);
      }
    }
    __syncthreads();
  }

  const int q4 = (lane >> 4) * 4, colb = lane & 15;
  #pragma unroll
  for (int n = 0; n < 8; n++) {
    int gcol = ncol0 + n * 16 + colb;
    float bv = bias ? bias[gcol] : 0.f;
    #pragma unroll
    for (int q = 0; q < 4; q++) {
      int grow = vbase + (wave << 4) + q4 + q;
      if (grow >= V) continue;
      float o = acc[n][q] + bv;
      size_t idx = (size_t)grow * CO + gcol;
      if (RES) o += res[idx];
      if (RELU) o = fmaxf(o, 0.f);
      if (OBF16) ((u16*)OUT)[idx] = f2bf(o);
      else {
        ((float*)OUT)[idx] = o;
        if (OUTB) OUTB[idx] = f2bf(o);
      }
    }
  }
}

// =====================================================================
// Fused C3-block MLP: h1=relu([x|gf|E]@w0+b0); h2=relu(h1@w1+b1);
// out = h2@w2 + b2 + res  -> XM f32 (+ SHB bf16 shadow).
// h1/h2 live in a 20KB LDS tile (bf16, same rounding as the split path).
// BM=64 rows, all 128 cols in-block, 4 waves.
// =====================================================================
__global__ __launch_bounds__(256)
void k_mlp3(const u16* __restrict__ A0, const u16* __restrict__ A1,
            const u16* __restrict__ A2,                     // [V][128] each
            const u16* __restrict__ w0t,                    // [128][384]
            const u16* __restrict__ w1t, const u16* __restrict__ w2t, // [128][128]
            const float* __restrict__ b0, const float* __restrict__ b1,
            const float* __restrict__ b2,
            float* __restrict__ XM, u16* __restrict__ SHB, int V)
{
  __shared__ __align__(16) u16 As[64 * 40];
  __shared__ __align__(16) u16 Ws[128 * 40];
  __shared__ __align__(16) u16 Hs[4][64 * 40];   // h tile [k-chunk][row][oct]

  const int tid  = threadIdx.x;
  const int wave = tid >> 6, lane = tid & 63;
  const int vbase = blockIdx.x * 64;
  const int ar = tid >> 2, ac = tid & 3;
  const int arow = vbase + ar;
  const bool rok = arow < V;
  const int mrow = (wave << 4) + (lane & 15);
  const int kc = lane >> 4;
  const int q4 = (lane >> 4) * 4, colb = lane & 15;

  f32x4 acc[8];
  auto zacc = [&]{
    #pragma unroll
    for (int n = 0; n < 8; n++) { acc[n][0]=0.f; acc[n][1]=0.f; acc[n][2]=0.f; acc[n][3]=0.f; }
  };
  // write relu(acc+b) into Hs as bf16 (A-fragment layout for next phase)
  auto hwrite = [&](const float* b){
    #pragma unroll
    for (int n = 0; n < 8; n++) {
      int c = n * 16 + colb;
      float bv = b[c];
      #pragma unroll
      for (int q = 0; q < 4; q++) {
        int row = (wave << 4) + q4 + q;
        Hs[c >> 5][lofs(row, (c >> 3) & 3) + (c & 7)] = f2bf(fmaxf(acc[n][q] + bv, 0.f));
      }
    }
  };
  auto mfma_tile = [&](const u16* a8){
    short8v a = *(const short8v*)(const void*)a8;
    #pragma unroll
    for (int n = 0; n < 8; n++) {
      short8v b = *(const short8v*)(const void*)&Ws[(n * 16 + (lane & 15)) * 40 + kc * 8];
      acc[n] = __builtin_amdgcn_mfma_f32_16x16x32_bf16(a, b, acc[n], 0, 0, 0);
    }
  };

  // ---------- phase 1: KT=384 over [A0|A1|A2], weights w0t ----------
  zacc();
  for (int kt = 0; kt < 384; kt += 32) {
    {
      int kg = kt + ac * 8;
      const u16* src = (kg < 128) ? A0 : (kg < 256) ? A1 : A2;
      int kl = kg & 127;
      uint4 aw = make_uint4(0,0,0,0);
      if (rok) aw = *(const uint4*)(src + (size_t)arow * 128 + kl);
      *(uint4*)&As[ar * 40 + ac * 8] = aw;
    }
    #pragma unroll
    for (int i = 0; i < 2; i++) {
      int col = tid & 127, c = (tid >> 7) + 2 * i;
      *(uint4*)&Ws[col * 40 + c * 8] =
        *(const uint4*)(w0t + (size_t)col * 384 + kt + c * 8);
    }
    __syncthreads();
    mfma_tile(&As[mrow * 40 + kc * 8]);
    __syncthreads();
  }
  hwrite(b0);
  // ---------- phase 2: K=128 over Hs, weights w1t ----------
  zacc();
  for (int kt = 0; kt < 128; kt += 32) {
    #pragma unroll
    for (int i = 0; i < 2; i++) {
      int col = tid & 127, c = (tid >> 7) + 2 * i;
      *(uint4*)&Ws[col * 40 + c * 8] =
        *(const uint4*)(w1t + (size_t)col * 128 + kt + c * 8);
    }
    __syncthreads();   // orders hwrite + Ws stage before reads
    mfma_tile(&Hs[kt >> 5][lofs(mrow, kc)]);
    __syncthreads();
  }
  hwrite(b1);
  // ---------- phase 3: K=128 over Hs, weights w2t + residual epilogue ----------
  zacc();
  for (int kt = 0; kt < 128; kt += 32) {
    #pragma unroll
    for (int i = 0; i < 2; i++) {
      int col = tid & 127, c = (tid >> 7) + 2 * i;
      *(uint4*)&Ws[col * 40 + c * 8] =
        *(const uint4*)(w2t + (size_t)col * 128 + kt + c * 8);
    }
    __syncthreads();
    mfma_tile(&Hs[kt >> 5][lofs(mrow, kc)]);
    __syncthreads();
  }
  #pragma unroll
  for (int n = 0; n < 8; n++) {
    int gcol = n * 16 + colb;
    float bv = b2[gcol];
    #pragma unroll
    for (int q = 0; q < 4; q++) {
      int grow = vbase + (wave << 4) + q4 + q;
      if (grow >= V) continue;
      size_t idx = (size_t)grow * C3 + gcol;
      float o = acc[n][q] + bv + XM[idx];
      XM[idx] = o;
      SHB[idx] = f2bf(o);
    }
  }
}

// =====================================================================
// Register-resident MFMA megagate (no LDS, no barriers).
// =====================================================================
__global__ __launch_bounds__(256)
void k_mgate_reg(const u16* __restrict__ GEX, const u16* __restrict__ GEY,
                 const u16* __restrict__ pS, const u16* __restrict__ pR,
                 const u16* __restrict__ pI,
                 u16* __restrict__ GF, int CO, int V)
{
  const int lane = threadIdx.x & 63;
  const int wave = threadIdx.x >> 6;
  const int rbase = blockIdx.x * 128 + wave * 32;
  const int arow = rbase + (lane & 31);
  const int koff = (lane >> 5) * 8;
  const bool rok = arow < V;

  uint4 ax[8], ay[8], an[8];
  #pragma unroll
  for (int kt = 0; kt < 8; kt++) {
    uint4 zx = make_uint4(0,0,0,0), zy = make_uint4(0,0,0,0);
    if (rok) {
      zx = *(const uint4*)(GEX + (size_t)arow * KE + kt * 16 + koff);
      zy = *(const uint4*)(GEY + (size_t)arow * KE + kt * 16 + koff);
    }
    ax[kt] = zx; ay[kt] = zy;
    an[kt] = make_uint4(zy.x ^ 0x80008000u, zy.y ^ 0x80008000u,
                        zy.z ^ 0x80008000u, zy.w ^ 0x80008000u);
  }

  const int ngr = CO >> 5;
  for (int g = 0; g < ngr; g++) {
    f32x16 gx, gy, br, bi;
    #pragma unroll
    for (int r = 0; r < 16; r++) { gx[r]=0.f; gy[r]=0.f; br[r]=0.f; bi[r]=0.f; }
    #pragma unroll
    for (int kt = 0; kt < 8; kt++) {
      size_t bo = ((size_t)(g * 8 + kt) * 64 + lane) * 8;
      short8v bs  = *(const short8v*)(const void*)(pS + bo);
      short8v brv = *(const short8v*)(const void*)(pR + bo);
      short8v biv = *(const short8v*)(const void*)(pI + bo);
      short8v axv = as8(ax[kt]), ayv = as8(ay[kt]), anv = as8(an[kt]);
      gx = __builtin_amdgcn_mfma_f32_32x32x16_bf16(axv, bs,  gx, 0, 0, 0);
      gy = __builtin_amdgcn_mfma_f32_32x32x16_bf16(ayv, bs,  gy, 0, 0, 0);
      br = __builtin_amdgcn_mfma_f32_32x32x16_bf16(axv, brv, br, 0, 0, 0);
      br = __builtin_amdgcn_mfma_f32_32x32x16_bf16(anv, biv, br, 0, 0, 0);
      bi = __builtin_amdgcn_mfma_f32_32x32x16_bf16(axv, biv, bi, 0, 0, 0);
      bi = __builtin_amdgcn_mfma_f32_32x32x16_bf16(ayv, brv, bi, 0, 0, 0);
    }
    const int col = g * 32 + (lane & 31);
    const int rhi = 4 * (lane >> 5);
    #pragma unroll
    for (int r = 0; r < 16; r++) {
      int row = rbase + (r & 3) + 8 * (r >> 2) + rhi;
      if (row < V) {
        float o = tanhf(gx[r] * br[r] + gy[r] * bi[r]);
        GF[(size_t)row * CO + col] = f2bf(o);
      }
    }
  }
}

// =====================================================================
// MFMA spectral down-projection (bf16 inputs), split-K + f32 atomics.
// =====================================================================
__global__ __launch_bounds__(256)
void k_specmm(const u16* __restrict__ E, const u16* __restrict__ X,
              const float* __restrict__ mass, float* __restrict__ SPEC,
              int C, int V, int CH)
{
  __shared__ __align__(16) u16 As[64 * 40];
  __shared__ __align__(16) u16 Bs[128 * 40];

  const int tid = threadIdx.x;
  const int wave = tid >> 6, lane = tid & 63;
  const int m0 = blockIdx.y * 64;
  const int n0 = blockIdx.z * 128;
  const int vs = blockIdx.x * CH;
  const int ve = min(V, vs + CH);

  f32x4 acc[8];
  #pragma unroll
  for (int n = 0; n < 8; n++) { acc[n][0]=0.f; acc[n][1]=0.f; acc[n][2]=0.f; acc[n][3]=0.f; }

  const int am = tid & 63, ac = tid >> 6;
  const int bcol = tid & 127, bc0 = (tid >> 7) * 2;

  u16 ea[8]; float fb0[8], fb1[8], fm0[8], fm1[8];
  auto loadA = [&](int kt) {
    #pragma unroll
    for (int j = 0; j < 8; j++) {
      int v = kt + ac * 8 + j;
      ea[j] = (v < ve) ? E[(size_t)v * KE + m0 + am] : (u16)0;
    }
  };
  auto loadB = [&](int kt) {
    #pragma unroll
    for (int j = 0; j < 8; j++) {
      int v0 = kt + bc0 * 8 + j, v1 = v0 + 8;
      fb0[j] = (v0 < ve) ? bf2f(X[(size_t)v0 * C + n0 + bcol]) : 0.f;
      fm0[j] = (v0 < ve) ? mass[v0] : 0.f;
      fb1[j] = (v1 < ve) ? bf2f(X[(size_t)v1 * C + n0 + bcol]) : 0.f;
      fm1[j] = (v1 < ve) ? mass[v1] : 0.f;
    }
  };
  loadA(vs); loadB(vs);

  for (int kt = vs; kt < ve; kt += 32) {
    __syncthreads();
    *(uint4*)&As[lofs(am, ac)] = make_uint4(
        (u32)ea[0] | ((u32)ea[1] << 16), (u32)ea[2] | ((u32)ea[3] << 16),
        (u32)ea[4] | ((u32)ea[5] << 16), (u32)ea[6] | ((u32)ea[7] << 16));
    float t0[8], t1[8];
    #pragma unroll
    for (int j = 0; j < 8; j++) { t0[j] = fb0[j]*fm0[j]; t1[j] = fb1[j]*fm1[j]; }
    *(uint4*)&Bs[lofs(bcol, bc0)] = make_uint4(
        pk2(t0[0],t0[1]), pk2(t0[2],t0[3]), pk2(t0[4],t0[5]), pk2(t0[6],t0[7]));
    *(uint4*)&Bs[lofs(bcol, bc0 + 1)] = make_uint4(
        pk2(t1[0],t1[1]), pk2(t1[2],t1[3]), pk2(t1[4],t1[5]), pk2(t1[6],t1[7]));
    __syncthreads();
    if (kt + 32 < ve) { loadA(kt + 32); loadB(kt + 32); }
    const int kc = lane >> 4, ml = lane & 15;
    short8v a = *(const short8v*)(const void*)&As[lofs(wave * 16 + ml, kc)];
    #pragma unroll
    for (int n = 0; n < 8; n++) {
      short8v b = *(const short8v*)(const void*)&Bs[lofs(n * 16 + ml, kc)];
      acc[n] = __builtin_amdgcn_mfma_f32_16x16x32_bf16(a, b, acc[n], 0, 0, 0);
    }
  }

  const int q4 = (lane >> 4) * 4, colb = lane & 15;
  #pragma unroll
  for (int n = 0; n < 8; n++) {
    int col = n0 + n * 16 + colb;
    #pragma unroll
    for (int q = 0; q < 4; q++) {
      int row = m0 + wave * 16 + q4 + q;
      unsafeAtomicAdd(&SPEC[(size_t)row * C + col], acc[n][q]);
    }
  }
}

// =====================================================================
// smallprep: packed B-fragment S/Tr/Ti + SWt
// =====================================================================
template<int C>
__global__ void k_smallprep(const float* __restrict__ SPEC, const float* __restrict__ evals,
                            const float* __restrict__ dt, const float* __restrict__ Are,
                            const float* __restrict__ Aim, const float* __restrict__ w0,
                            u16* __restrict__ pS, u16* __restrict__ pR,
                            u16* __restrict__ pI, u16* __restrict__ SWt)
{
  __shared__ float sld[C];
  const int k = blockIdx.x;
  const int c = threadIdx.x;
  const float ev = evals[k];
  float s = expf(-ev * fmaxf(dt[c], 1e-8f)) * SPEC[(size_t)k * C + c];
  sld[c] = s;
  const size_t pidx = ((size_t)((c >> 5) * 8 + (k >> 4)) * 64
                       + (c & 31) + ((k >> 3) & 1) * 32) * 8 + (k & 7);
  pS[pidx] = f2bf(s);
  __syncthreads();
  float tr = 0.f, ti = 0.f, sw = 0.f;
  for (int j = 0; j < C; j++) {
    float sj = sld[j];
    tr = fmaf(sj, Are[(size_t)j * C + c], tr);
    ti = fmaf(sj, Aim[(size_t)j * C + c], ti);
    sw = fmaf(sj, w0[(size_t)(C + j) * C + c], sw);
  }
  pR[pidx] = f2bf(tr);
  pI[pidx] = f2bf(ti);
  SWt[(size_t)c * 128 + k] = f2bf(sw);
}

// ===== weight pre-transpose f32[K][N] -> bf16 Wt[N][K] (z batches) =====
__global__ void k_prepw(const float* __restrict__ W, u16* __restrict__ WT, int K, int N) {
  size_t zoff = (size_t)blockIdx.z * K * N;
  int i = blockIdx.x * 256 + threadIdx.x;
  if (i < K * N) {
    int k = i / N, n = i % N;
    WT[zoff + (size_t)n * K + k] = f2bf(W[zoff + i]);
  }
}

// ===== f32 -> bf16 elementwise (n % 4 == 0) =====
__global__ void k_cvt(const float* __restrict__ in, u16* __restrict__ out, int n) {
  int i = (blockIdx.x * 256 + threadIdx.x) * 4;
  if (i < n) {
    float4 v = ld4(in + i);
    ushort4 o; o.x = f2bf(v.x); o.y = f2bf(v.y); o.z = f2bf(v.z); o.w = f2bf(v.w);
    *(ushort4*)(out + i) = o;
  }
}

// ============================ CSR build ==============================
__global__ void k_hist(const int* __restrict__ idx, int* __restrict__ deg, int E) {
  int e = blockIdx.x * 256 + threadIdx.x;
  if (e < E) atomicAdd(&deg[idx[2 * e]], 1);
}
__global__ void k_scan1(const int* __restrict__ deg, int* __restrict__ excl,
                        int* __restrict__ bsum, int V) {
  __shared__ int sd[256];
  int t = threadIdx.x;
  int i = blockIdx.x * 256 + t;
  int v = (i < V) ? deg[i] : 0;
  sd[t] = v;
  __syncthreads();
  for (int off = 1; off < 256; off <<= 1) {
    int add = (t >= off) ? sd[t - off] : 0;
    __syncthreads();
    sd[t] += add;
    __syncthreads();
  }
  if (i < V) excl[i] = sd[t] - v;
  if (t == 255) bsum[blockIdx.x] = sd[255];
}
__global__ void k_scan2(int* __restrict__ bsum, int nb, int* __restrict__ rowptr, int V) {
  __shared__ int sd[512];
  int t = threadIdx.x;
  int v = (t < nb) ? bsum[t] : 0;
  sd[t] = v;
  __syncthreads();
  for (int off = 1; off < 512; off <<= 1) {
    int add = (t >= off) ? sd[t - off] : 0;
    __syncthreads();
    sd[t] += add;
    __syncthreads();
  }
  if (t < nb) bsum[t] = sd[t] - v;
  if (t == 0) rowptr[V] = sd[511];
}
__global__ void k_scan3(const int* __restrict__ excl, const int* __restrict__ bsum,
                        int* __restrict__ rowptr, int V) {
  int i = blockIdx.x * 256 + threadIdx.x;
  if (i < V) rowptr[i] = excl[i] + bsum[i >> 8];
}
__global__ void k_scatter(const int* __restrict__ idx, const float* __restrict__ val,
                          const int* __restrict__ rowptr, int* __restrict__ cur,
                          int* __restrict__ ecol, float* __restrict__ eval, int E) {
  int e = blockIdx.x * 256 + threadIdx.x;
  if (e < E) {
    int d = idx[2 * e];
    int p = rowptr[d] + atomicAdd(&cur[d], 1);
    ecol[p] = idx[2 * e + 1];
    eval[p] = val[e];
  }
}
// GE[r][:] = sum val * Ebf16[col][:]  (256B bf16 row gathers)
__global__ __launch_bounds__(256)
void k_spmm_csr(const int* __restrict__ rowptr, const int* __restrict__ ecol,
                const float* __restrict__ eval, const u16* __restrict__ E,
                u16* __restrict__ GE, int V) {
  int r = blockIdx.x * 8 + (threadIdx.x >> 5);
  int lane = threadIdx.x & 31;
  if (r >= V) return;
  int j1 = rowptr[r + 1];
  float4 a = make_float4(0.f,0.f,0.f,0.f);
  for (int j = rowptr[r]; j < j1; j++) {
    int c = ecol[j];
    float v = eval[j];
    ushort4 x = *(const ushort4*)(E + (size_t)c * KE + lane * 4);
    a.x = fmaf(v, bf2f(x.x), a.x); a.y = fmaf(v, bf2f(x.y), a.y);
    a.z = fmaf(v, bf2f(x.z), a.z); a.w = fmaf(v, bf2f(x.w), a.w);
  }
  ushort4 o;
  o.x = f2bf(a.x); o.y = f2bf(a.y); o.z = f2bf(a.z); o.w = f2bf(a.w);
  *(ushort4*)(GE + (size_t)r * KE + lane * 4) = o;
}

// ============================ segment max ============================
__global__ void k_segmax_init(unsigned* __restrict__ u, int n) {
  int i = blockIdx.x * 256 + threadIdx.x;
  if (i < n) u[i] = 0x007FFFFFu;
}
__global__ void k_segmax_scatter(const float* __restrict__ X, const int* __restrict__ tr,
                                 unsigned* __restrict__ u) {
  int i = blockIdx.x * 256 + threadIdx.x;
  if (i >= V3 * C3) return;
  int v = i >> 7, c = i & 127;
  unsigned b = __float_as_uint(X[i]);
  unsigned m = (b & 0x80000000u) ? ~b : (b | 0x80000000u);
  atomicMax(&u[((size_t)tr[v] << 7) + c], m);
}
__global__ void k_segmax_decode(const unsigned* __restrict__ u, float* __restrict__ out, int n) {
  int i = blockIdx.x * 256 + threadIdx.x;
  if (i < n) {
    unsigned m = u[i];
    float f = 0.f;
    if (m != 0x007FFFFFu) {
      unsigned b = (m & 0x80000000u) ? (m & 0x7FFFFFFFu) : ~m;
      f = __uint_as_float(b);
    }
    out[i] = f;
  }
}

// ========================= final projection ==========================
__global__ __launch_bounds__(256)
void k_outproj(const float* __restrict__ Y, const float* __restrict__ W,
               const float* __restrict__ B, float* __restrict__ OUT, int V) {
  __shared__ float Wl[128][22];
  __shared__ float ys[8][128];
  const int tid = threadIdx.x;
  for (int f = tid; f < 128 * 21; f += 256) Wl[f / 21][f % 21] = W[f];
  {
    int r = tid >> 5, cc = (tid & 31) * 4;
    int v = blockIdx.x * 8 + r;
    float4 yv = make_float4(0.f,0.f,0.f,0.f);
    if (v < V) yv = ld4(Y + (size_t)v * C3 + cc);
    st4(&ys[r][cc], yv);
  }
  __syncthreads();
  int r = tid >> 5, c = tid & 31;
  int v = blockIdx.x * 8 + r;
  if (v < V && c < 21) {
    float acc = B[c];
    #pragma unroll 8
    for (int k = 0; k < 128; k++) acc = fmaf(ys[r][k], Wl[k][c], acc);
    OUT[(size_t)v * 21 + c] = acc;
  }
}

// =====================================================================
extern "C" void kernel_launch(void* const* d_in, const int* in_sizes, int n_in,
                              void* d_out, int out_size, void* d_ws, size_t ws_size,
                              hipStream_t stream)
{
  (void)in_sizes; (void)n_in; (void)out_size;
  const float* x_in    = (const float*)d_in[0];
  const float* mass3   = (const float*)d_in[1];
  const float* evals3  = (const float*)d_in[2];
  const float* evecs3  = (const float*)d_in[3];
  const int*   gX3i    = (const int*)d_in[4];
  const float* gX3v    = (const float*)d_in[5];
  const int*   gY3i    = (const int*)d_in[6];
  const float* gY3v    = (const float*)d_in[7];
  const float* massm   = (const float*)d_in[8];
  const float* evalsm  = (const float*)d_in[9];
  const float* evecsm  = (const float*)d_in[10];
  const int*   gXmi    = (const int*)d_in[11];
  const float* gXmv    = (const float*)d_in[12];
  const int*   gYmi    = (const int*)d_in[13];
  const float* gYmv    = (const float*)d_in[14];
  const int*   tr34    = (const int*)d_in[15];
  const float* in_w    = (const float*)d_in[16];
  const float* in_b    = (const float*)d_in[17];
  const float* widen_w = (const float*)d_in[18];
  const float* widen_b = (const float*)d_in[19];
  const float* narrow_w= (const float*)d_in[20];
  const float* narrow_b= (const float*)d_in[21];
  const float* halve_w = (const float*)d_in[22];
  const float* halve_b = (const float*)d_in[23];
  const float* out_w   = (const float*)d_in[24];
  const float* out_b   = (const float*)d_in[25];
  const float* enc_p[9]; const float* mid_p[9]; const float* dec_p[9];
  for (int i = 0; i < 9; i++) {
    enc_p[i] = (const float*)d_in[26 + i];
    mid_p[i] = (const float*)d_in[35 + i];
    dec_p[i] = (const float*)d_in[44 + i];
  }

  // ---------------- workspace layout (~214 MB) ----------------
  char* ws = (char*)d_ws;
  size_t off = 0;
  float* XM  = (float*)(ws + off); off += (size_t)V3 * C3 * 4;
  u16* SHB   = (u16*)(ws + off);   off += (size_t)V3 * C3 * 2;
  u16* GEX3  = (u16*)(ws + off);   off += (size_t)V3 * KE * 2;
  u16* GEY3  = (u16*)(ws + off);   off += (size_t)V3 * KE * 2;
  u16* GEXm  = (u16*)(ws + off);   off += (size_t)VM * KE * 2;
  u16* GEYm  = (u16*)(ws + off);   off += (size_t)VM * KE * 2;
  u16* BSCR  = (u16*)(ws + off);   off += (size_t)V3 * C3 * 2;
  char* E3R  = (char*)(ws + off);  off += (size_t)V3 * KE * 2;
  u16* Embf  = (u16*)(ws + off);   off += (size_t)VM * KE * 2;
  u16* SHM   = (u16*)(ws + off);   off += (size_t)VM * CMID * 2;
  float* spec= (float*)(ws + off); off += 131072;
  u16* pS  = (u16*)(ws + off); off += 65536;
  u16* pR  = (u16*)(ws + off); off += 65536;
  u16* pI  = (u16*)(ws + off); off += 65536;
  u16* SWt = (u16*)(ws + off); off += 65536;
  u16* wT  = (u16*)(ws + off); off += 2400000;
  const size_t NEED = off;
  if (ws_size < NEED) return;

  u16*   E3bf = (u16*)E3R;
  float* M0   = (float*)E3R;
  int*   rowptr = (int*)BSCR;
  int*   deg    = (int*)((char*)BSCR + 400128);
  int*   ecol   = (int*)((char*)BSCR + 800256);
  float* evalv  = (float*)((char*)BSCR + 4000256);
  int*   bsum   = (int*)((char*)BSCR + 7200256);
  unsigned* xm_u  = (unsigned*)BSCR;
  float*    xm_dec= (float*)((char*)BSCR + 12800000);
  u16* BSCR0 = BSCR;
  u16* BSCR1 = BSCR + (size_t)VM * CMID;

  u16* in_wt    = wT + 0;
  u16* widen_t  = wT + 2048;
  u16* narrow_t = wT + 34816;
  u16* halve_t  = wT + 67584;
  u16* enc_w0t  = wT + 100352;
  u16* enc_w1t  = wT + 198656;
  u16* enc_w2t  = wT + 231424;
  u16* mid_w0t  = wT + 264192;
  u16* mid_w1t  = wT + 657408;
  u16* mid_w2t  = wT + 788480;
  u16* dec_w0t  = wT + 919552;
  u16* dec_w1t  = wT + 1017856;
  u16* dec_w2t  = wT + 1050624;

  auto prepw = [&](const float* W, u16* WT, int K, int N, int z) {
    k_prepw<<<dim3(cdiv(K * N, 256), 1, z), 256, 0, stream>>>(W, WT, K, N);
  };
  prepw(in_w, in_wt, 16, 128, 1);
  prepw(widen_w, widen_t, 128, 256, 1);
  prepw(narrow_w, narrow_t, 256, 128, 1);
  prepw(halve_w, halve_t, 256, 128, 1);
  prepw(enc_p[3], enc_w0t, 384, 128, 2);
  prepw(enc_p[5], enc_w1t, 128, 128, 2);
  prepw(enc_p[7], enc_w2t, 128, 128, 2);
  prepw(mid_p[3], mid_w0t, 768, 256, 2);
  prepw(mid_p[5], mid_w1t, 256, 256, 2);
  prepw(mid_p[7], mid_w2t, 256, 256, 2);
  prepw(dec_p[3], dec_w0t, 384, 128, 2);
  prepw(dec_p[5], dec_w1t, 128, 128, 2);
  prepw(dec_p[7], dec_w2t, 128, 128, 2);

  // evecs -> bf16 FIRST (spmm gathers bf16 now)
  k_cvt<<<cdiv(V3 * KE / 4, 256), 256, 0, stream>>>(evecs3, E3bf, V3 * KE);
  k_cvt<<<cdiv(VM * KE / 4, 256), 256, 0, stream>>>(evecsm, Embf, VM * KE);

  auto build_ge = [&](const int* idx, const float* val, int E_, int V_,
                      const u16* Ebf, u16* GE) {
    hipMemsetAsync(deg, 0, (size_t)V_ * 4, stream);
    k_hist<<<cdiv(E_, 256), 256, 0, stream>>>(idx, deg, E_);
    int nb = cdiv(V_, 256);
    k_scan1<<<nb, 256, 0, stream>>>(deg, ecol, bsum, V_);
    k_scan2<<<1, 512, 0, stream>>>(bsum, nb, rowptr, V_);
    k_scan3<<<nb, 256, 0, stream>>>(ecol, bsum, rowptr, V_);
    hipMemsetAsync(deg, 0, (size_t)V_ * 4, stream);
    k_scatter<<<cdiv(E_, 256), 256, 0, stream>>>(idx, val, rowptr, deg, ecol, evalv, E_);
    k_spmm_csr<<<cdiv(V_, 8), 256, 0, stream>>>(rowptr, ecol, evalv, Ebf, GE, V_);
  };
  build_ge(gX3i, gX3v, E3, V3, E3bf, GEX3);
  build_ge(gY3i, gY3v, E3, V3, E3bf, GEY3);
  build_ge(gXmi, gXmv, EM, VM, Embf, GEXm);
  build_ge(gYmi, gYmv, EM, VM, Embf, GEYm);

  const int G3 = cdiv(V3, 64);   // 1563
  const int GM = cdiv(VM, 64);   // 391

  // ---- block3: fused MLP ----
  auto run_block3 = [&](const float* p[9],
                        const u16* w0t, const u16* w1t, const u16* w2t, int i) {
    const float* dt  = p[0] + (size_t)i * C3;
    const float* Are = p[1] + (size_t)i * C3 * C3;
    const float* Aim = p[2] + (size_t)i * C3 * C3;
    const float* w0  = p[3] + (size_t)i * 3 * C3 * C3;
    const float* b0  = p[4] + (size_t)i * C3;
    const float* b1  = p[6] + (size_t)i * C3;
    const float* b2  = p[8] + (size_t)i * C3;
    const u16* w0ti = w0t + (size_t)i * 3 * C3 * C3;
    const u16* w1ti = w1t + (size_t)i * C3 * C3;
    const u16* w2ti = w2t + (size_t)i * C3 * C3;
    hipMemsetAsync(spec, 0, (size_t)KE * C3 * 4, stream);
    k_specmm<<<dim3(cdiv(V3, 256), 2, 1), 256, 0, stream>>>(E3bf, SHB, mass3, spec, C3, V3, 256);
    k_smallprep<C3><<<KE, C3, 0, stream>>>(spec, evals3, dt, Are, Aim, w0, pS, pR, pI, SWt);
    k_mgate_reg<<<cdiv(V3, 128), 256, 0, stream>>>(GEX3, GEY3, pS, pR, pI, BSCR, C3, V3);
    // NOTE: x-part of w0 uses SWt trick only for xd; A-concat = [SHB | gf | E3bf],
    // with SWt folded in as the E3bf-partner weight in slot 2:
    k_mlp3<<<G3, 256, 0, stream>>>(SHB, BSCR, E3bf,
                                   /*w0t built below*/ nullptr, w1ti, w2ti,
                                   b0, b1, b2, XM, SHB, V3);
  };
  (void)run_block3; // replaced by explicit calls below (w0t layout differs)

  // The fused kernel needs w0t as [128 cols][384 k] where k-segments are
  // {x (w0a), gf (w0c), evecs (SWt)}. w0a/w0c are static; SWt changes per
  // block. Build a per-block combined weight into wCmb (128*384 u16).
  u16* wCmb = wT + 1083392;   // 98304 elems fits in wT tail (wT cap 1,200,000)

  auto run_block3x = [&](const float* p[9],
                         const u16* w0t, const u16* w1t, const u16* w2t, int i) {
    const float* dt  = p[0] + (size_t)i * C3;
    const float* Are = p[1] + (size_t)i * C3 * C3;
    const float* Aim = p[2] + (size_t)i * C3 * C3;
    const float* w0  = p[3] + (size_t)i * 3 * C3 * C3;
    const float* b0  = p[4] + (size_t)i * C3;
    const float* b1  = p[6] + (size_t)i * C3;
    const float* b2  = p[8] + (size_t)i * C3;
    const u16* w0ti = w0t + (size_t)i * 3 * C3 * C3;   // [128][384]: x|xd|gf k-order
    const u16* w1ti = w1t + (size_t)i * C3 * C3;
    const u16* w2ti = w2t + (size_t)i * C3 * C3;
    hipMemsetAsync(spec, 0, (size_t)KE * C3 * 4, stream);
    k_specmm<<<dim3(cdiv(V3, 256), 2, 1), 256, 0, stream>>>(E3bf, SHB, mass3, spec, C3, V3, 256);
    k_smallprep<C3><<<KE, C3, 0, stream>>>(spec, evals3, dt, Are, Aim, w0, pS, pR, pI, SWt);
    k_mgate_reg<<<cdiv(V3, 128), 256, 0, stream>>>(GEX3, GEY3, pS, pR, pI, BSCR, C3, V3);
    // assemble wCmb[col][0:128]=w0t_x, [128:256]=w0t_gf, [256:384]=SWt
    hipMemcpyAsync(wCmb, nullptr, 0, hipMemcpyDeviceToDevice, stream); // no-op keep
    k_mlp3<<<G3, 256, 0, stream>>>(SHB, BSCR, E3bf, wCmb, w1ti, w2ti,
                                   b0, b1, b2, XM, SHB, V3);
    (void)w0ti;
  };
  (void)run_block3x;

  // Simplest correct assembly: small kernel to build wCmb each block.
  auto launch_block3 = [&](const float* p[9],
                           const u16* w0t, const u16* w1t, const u16* w2t, int i) {
    const float* dt  = p[0] + (size_t)i * C3;
    const float* Are = p[1] + (size_t)i * C3 * C3;
    const float* Aim = p[2] + (size_t)i * C3 * C3;
    const float* w0  = p[3] + (size_t)i * 3 * C3 * C3;
    const float* b0  = p[4] + (size_t)i * C3;
    const float* b1  = p[6] + (size_t)i * C3;
    const float* b2  = p[8] + (size_t)i * C3;
    const u16* w0ti = w0t + (size_t)i * 3 * C3 * C3;   // [col][384] k-order x|xd|gf
    const u16* w1ti = w1t + (size_t)i * C3 * C3;
    const u16* w2ti = w2t + (size_t)i * C3 * C3;
    hipMemsetAsync(spec, 0, (size_t)KE * C3 * 4, stream);
    k_specmm<<<dim3(cdiv(V3, 256), 2, 1), 256, 0, stream>>>(E3bf, SHB, mass3, spec, C3, V3, 256);
    k_smallprep<C3><<<KE, C3, 0, stream>>>(spec, evals3, dt, Are, Aim, w0, pS, pR, pI, SWt);
    k_mgate_reg<<<cdiv(V3, 128), 256, 0, stream>>>(GEX3, GEY3, pS, pR, pI, BSCR, C3, V3);
    // build wCmb: [col][0:128]=w0ti[col][0:128](x), [128:256]=w0ti[col][256:384](gf),
    //             [256:384]=SWt[col][:]
    struct L { static __global__ void k(const u16* w0t_, const u16* swt_, u16* o_) {
      int col = blockIdx.x, t = threadIdx.x;   // 128 blocks x 128 threads
      o_[(size_t)col * 384 + t]        = w0t_[(size_t)col * 384 + t];
      o_[(size_t)col * 384 + 128 + t]  = w0t_[(size_t)col * 384 + 256 + t];
      o_[(size_t)col * 384 + 256 + t]  = swt_[(size_t)col * 128 + t];
    } };
    L::k<<<128, 128, 0, stream>>>(w0ti, SWt, wCmb);
    k_mlp3<<<G3, 256, 0, stream>>>(SHB, BSCR, E3bf, wCmb, w1ti, w2ti,
                                   b0, b1, b2, XM, SHB, V3);
  };

  // ---- blockm: split (proven) ----
  auto run_blockm = [&](const float* p[9],
                        const u16* w0t, const u16* w1t, const u16* w2t, int i) {
    const float* dt  = p[0] + (size_t)i * CMID;
    const float* Are = p[1] + (size_t)i * CMID * CMID;
    const float* Aim = p[2] + (size_t)i * CMID * CMID;
    const float* w0  = p[3] + (size_t)i * 3 * CMID * CMID;
    const float* b0  = p[4] + (size_t)i * CMID;
    const float* b1  = p[6] + (size_t)i * CMID;
    const float* b2  = p[8] + (size_t)i * CMID;
    const u16* w0ti = w0t + (size_t)i * 3 * CMID * CMID;
    const u16* w1ti = w1t + (size_t)i * CMID * CMID;
    const u16* w2ti = w2t + (size_t)i * CMID * CMID;
    hipMemsetAsync(spec, 0, (size_t)KE * CMID * 4, stream);
    k_specmm<<<dim3(cdiv(VM, 128), 2, 2), 256, 0, stream>>>(Embf, SHM, massm, spec, CMID, VM, 128);
    k_smallprep<CMID><<<KE, CMID, 0, stream>>>(spec, evalsm, dt, Are, Aim, w0, pS, pR, pI, SWt);
    k_mgate_reg<<<cdiv(VM, 128), 256, 0, stream>>>(GEXm, GEYm, pS, pR, pI, BSCR0, CMID, VM);
    k_mgemm<true,false,false,true><<<dim3(GM, 2), 256, 0, stream>>>(
        SHM, 1, CMID, w0ti, 3*CMID, 0,
        BSCR0, 1, CMID, w0ti, 3*CMID, 2*CMID,
        Embf, 1, KE, SWt, 128, 0,
        nullptr, b0, nullptr, BSCR1, nullptr, CMID, VM);
    k_mgemm<true,false,false,true><<<dim3(GM, 2), 256, 0, stream>>>(
        BSCR1, 1, CMID, w1ti, CMID, 0,
        nullptr,0,0,nullptr,0,0, nullptr,0,0,nullptr,0,0,
        nullptr, b1, nullptr, BSCR0, nullptr, CMID, VM);
    k_mgemm<false,true,false,false><<<dim3(GM, 2), 256, 0, stream>>>(
        BSCR0, 1, CMID, w2ti, CMID, 0,
        nullptr,0,0,nullptr,0,0, nullptr,0,0,nullptr,0,0,
        nullptr, b2, M0, M0, SHM, CMID, VM);
  };

  // ---- encoder ----
  k_mgemm<true,false,false,false><<<dim3(G3, 1), 256, 0, stream>>>(
      x_in, 0, 16, in_wt, 16, 0,
      nullptr,0,0,nullptr,0,0, nullptr,0,0,nullptr,0,0,
      nullptr, in_b, nullptr, XM, SHB, C3, V3);
  launch_block3(enc_p, enc_w0t, enc_w1t, enc_w2t, 0);
  launch_block3(enc_p, enc_w0t, enc_w1t, enc_w2t, 1);        // x3 = XM / SHB

  // ---- pool ----
  k_segmax_init<<<cdiv(VM * C3, 256), 256, 0, stream>>>(xm_u, VM * C3);
  k_segmax_scatter<<<cdiv(V3 * C3, 256), 256, 0, stream>>>(XM, tr34, xm_u);
  k_segmax_decode<<<cdiv(VM * C3, 256), 256, 0, stream>>>(xm_u, xm_dec, VM * C3);
  k_mgemm<true,false,false,false><<<dim3(GM, 2), 256, 0, stream>>>(
      xm_dec, 0, C3, widen_t, C3, 0,
      nullptr,0,0,nullptr,0,0, nullptr,0,0,nullptr,0,0,
      nullptr, widen_b, nullptr, M0, SHM, CMID, VM);
  run_blockm(mid_p, mid_w0t, mid_w1t, mid_w2t, 0);
  run_blockm(mid_p, mid_w0t, mid_w1t, mid_w2t, 1);           // m_final shadow = SHM

  // ---- unpool ----
  k_mgemm<true,false,true,true><<<dim3(G3, 1), 256, 0, stream>>>(
      SHM, 1, CMID, narrow_t, CMID, 0,
      nullptr,0,0,nullptr,0,0, nullptr,0,0,nullptr,0,0,
      tr34, narrow_b, nullptr, BSCR, nullptr, C3, V3);
  k_mgemm<true,false,false,false><<<dim3(G3, 1), 256, 0, stream>>>(
      BSCR, 1, C3, halve_t, 2*C3, 0,
      SHB, 1, C3, halve_t, 2*C3, C3,
      nullptr,0,0,nullptr,0,0,
      nullptr, halve_b, nullptr, XM, SHB, C3, V3);

  // ---- decoder (rebuild E3bf: clobbered by M0 overlay) ----
  k_cvt<<<cdiv(V3 * KE / 4, 256), 256, 0, stream>>>(evecs3, E3bf, V3 * KE);
  launch_block3(dec_p, dec_w0t, dec_w1t, dec_w2t, 0);
  launch_block3(dec_p, dec_w0t, dec_w1t, dec_w2t, 1);

  // ---- output projection ----
  k_outproj<<<cdiv(V3, 8), 256, 0, stream>>>(XM, out_w, out_b, (float*)d_out, V3);
}